// Round 8
// baseline (1136.995 us; speedup 1.0000x reference)
//
#include <hip/hip_runtime.h>
#include <hip/hip_bf16.h>
#include <math.h>

#define BDIM 512
typedef __hip_bfloat16 bf16;

// Device buffers confirmed float32.
// Allocator model (r3-r7): VGPR budget behaves as if 2 blocks/CU regardless of
// hints: 512-thr -> 128 VGPR (good), 1024-thr -> 64 VGPR (spills). So occupancy
// must come from REAL 2 blocks/CU: LDS <= 80KB at BDIM=512.

__device__ __forceinline__ float sigm(float v)  { return 1.0f / (1.0f + __expf(-v)); }
__device__ __forceinline__ float ftanh(float v) { return 1.0f - 2.0f / (__expf(2.0f * v) + 1.0f); }
__device__ __forceinline__ float mod360(float v){ return v - 360.0f * floorf(v * (1.0f / 360.0f)); }

__device__ __forceinline__ float atan2_deg(float y, float x) {
  float ax = fabsf(x), ay = fabsf(y);
  float mx = fmaxf(ax, ay), mn = fminf(ax, ay);
  float r = mn / fmaxf(mx, 1e-30f);
  float r2 = r * r;
  float a = r * (0.99997726f + r2 * (-0.33262347f + r2 * (0.19354346f +
            r2 * (-0.11643287f + r2 * (0.05265332f - r2 * 0.01172120f)))));
  if (ay > ax) a = 1.5707963267948966f - a;
  if (x < 0.0f) a = 3.141592653589793f - a;
  a = copysignf(a, y);
  return a * 57.29577951308232f;
}

union EU {
  struct {
    alignas(16) float E[64][16];    // embedding (live: step start -> LSTM)
    alignas(16) float Emb[64][32];  // decoder spatial out (live: phase A -> LSTM)
  } eb;
  float Ctx[64][33];                // temporal ctx (live: temporal -> wtemp)
};

struct SmemCore {
  alignas(16) float H[64][32];     // carry h
  alignas(16) float C[64][32];     // carry c
  alignas(16) float HC[64][36];    // lstm out (stride 36: f4-aligned, bcast reads)
  alignas(16) EU u;
  alignas(16) float W[64][68];     // spatial weights
  float RS[64];
  bf16  WtT[64][32];               // W_temp^T bf16
  float Wemb[16][2];
  float Bemb[16];
  float BsumE[128], BsumD[128];
  float Dom[144];
  float Btemp[32];
  float Wout[2][32];
  float Bout[2];
  float Mask[64];
  float Pos[64][2];                // slow path only
  float Head[64];                  // slow path only
  float Xprev[64][2];
  float Xout[64][2];
  float MV[4];
};

template<bool GV> struct SmemT : SmemCore { float Enc[8][2112]; }; // fallback: Enc in LDS
template<> struct SmemT<true> : SmemCore {};                        // Enc in d_ws

static_assert(sizeof(SmemT<true>)  <= 64 * 1024, "core LDS over 64K");
static_assert(sizeof(SmemT<false>) <= 160 * 1024, "fallback LDS over budget");

// LSTM: weights streamed straight from global (L1-hot, 24KB). thread (k,pg) ->
// 4 gates x 4 peds. Acts (E, Hin) broadcast-read from LDS.
__device__ __forceinline__ void lstm_g(int tid, SmemCore& s,
    const float (*Hin)[32], const float* __restrict__ Wih,
    const float* __restrict__ Whh, const float* __restrict__ bsum) {
  const int k = tid & 31, pg = tid >> 5, p0 = pg * 4;
  const float4* W0i = (const float4*)&Wih[k * 16];
  const float4* W1i = (const float4*)&Wih[(32 + k) * 16];
  const float4* W2i = (const float4*)&Wih[(64 + k) * 16];
  const float4* W3i = (const float4*)&Wih[(96 + k) * 16];
  const float4* W0h = (const float4*)&Whh[k * 32];
  const float4* W1h = (const float4*)&Whh[(32 + k) * 32];
  const float4* W2h = (const float4*)&Whh[(64 + k) * 32];
  const float4* W3h = (const float4*)&Whh[(96 + k) * 32];
  float a0[4], a1[4], a2[4], a3[4];
  {
    const float b0 = bsum[k], b1 = bsum[32 + k], b2 = bsum[64 + k], b3 = bsum[96 + k];
    #pragma unroll
    for (int pi = 0; pi < 4; ++pi) { a0[pi] = b0; a1[pi] = b1; a2[pi] = b2; a3[pi] = b3; }
  }
  #pragma unroll
  for (int m4 = 0; m4 < 4; ++m4) {           // embedding part (K=16)
    float4 w0 = W0i[m4], w1 = W1i[m4], w2 = W2i[m4], w3 = W3i[m4];
    #pragma unroll
    for (int pi = 0; pi < 4; ++pi) {
      float4 xv = ((const float4*)s.u.eb.E[p0 + pi])[m4];
      a0[pi] += xv.x * w0.x + xv.y * w0.y + xv.z * w0.z + xv.w * w0.w;
      a1[pi] += xv.x * w1.x + xv.y * w1.y + xv.z * w1.z + xv.w * w1.w;
      a2[pi] += xv.x * w2.x + xv.y * w2.y + xv.z * w2.z + xv.w * w2.w;
      a3[pi] += xv.x * w3.x + xv.y * w3.y + xv.z * w3.z + xv.w * w3.w;
    }
  }
  #pragma unroll
  for (int m4 = 0; m4 < 8; ++m4) {           // hidden part (K=32)
    float4 w0 = W0h[m4], w1 = W1h[m4], w2 = W2h[m4], w3 = W3h[m4];
    #pragma unroll
    for (int pi = 0; pi < 4; ++pi) {
      float4 hv = ((const float4*)Hin[p0 + pi])[m4];
      a0[pi] += hv.x * w0.x + hv.y * w0.y + hv.z * w0.z + hv.w * w0.w;
      a1[pi] += hv.x * w1.x + hv.y * w1.y + hv.z * w1.z + hv.w * w1.w;
      a2[pi] += hv.x * w2.x + hv.y * w2.y + hv.z * w2.z + hv.w * w2.w;
      a3[pi] += hv.x * w3.x + hv.y * w3.y + hv.z * w3.z + hv.w * w3.w;
    }
  }
  #pragma unroll
  for (int pi = 0; pi < 4; ++pi) {
    const int p = p0 + pi;
    float iv = sigm(a0[pi]), fv = sigm(a1[pi]);
    float gv = ftanh(a2[pi]), ov = sigm(a3[pi]);
    float cn = fv * s.C[p][k] + iv * gv;
    s.C[p][k] = cn;
    s.HC[p][k] = ov * ftanh(cn);
  }
}

template<bool GV>
__global__ __launch_bounds__(BDIM, 2) void traj_fwd(
    const float* __restrict__ gx, const float* __restrict__ gdmat,
    const float* __restrict__ gbmat, const float* __restrict__ ghmat,
    const float* __restrict__ gimask,
    const float* __restrict__ gmean, const float* __restrict__ gvar,
    const float* __restrict__ gWemb, const float* __restrict__ gbemb,
    const float* __restrict__ gWihE, const float* __restrict__ gWhhE,
    const float* __restrict__ gbihE, const float* __restrict__ gbhhE,
    const float* __restrict__ gWihD, const float* __restrict__ gWhhD,
    const float* __restrict__ gbihD, const float* __restrict__ gbhhD,
    const float* __restrict__ gdom, const float* __restrict__ gWtemp,
    const float* __restrict__ gbtemp, const float* __restrict__ gWout,
    const float* __restrict__ gbout, float* __restrict__ gout,
    float* __restrict__ gws)
{
  __shared__ SmemT<GV> s;
  const int b = blockIdx.x, tid = threadIdx.x;
  float* __restrict__ encg = GV ? (gws + (size_t)b * 16384) : nullptr; // [8][64][32]

  // ---- stage constants; zero state ----
  for (int i = tid; i < 128; i += BDIM) {
    s.BsumE[i] = gbihE[i] + gbhhE[i];
    s.BsumD[i] = gbihD[i] + gbhhD[i];
  }
  for (int i = tid; i < 2048; i += BDIM) {
    int kp = i >> 6, m = i & 63;
    s.WtT[m][kp] = __float2bfloat16(gWtemp[i]);
  }
  for (int i = tid; i < 144; i += BDIM) s.Dom[i] = gdom[i];
  if (tid < 32) s.Btemp[tid] = gbtemp[tid];
  if (tid < 64) s.Wout[tid >> 5][tid & 31] = gWout[tid];
  if (tid < 2)  s.Bout[tid] = gbout[tid];
  if (tid < 16) s.Bemb[tid] = gbemb[tid];
  if (tid < 32) s.Wemb[tid >> 1][tid & 1] = gWemb[tid];
  if (tid < 4)  s.MV[tid] = (tid < 2) ? gmean[b * 2 + tid] : gvar[b * 2 + tid - 2];
  for (int i = tid; i < 2048; i += BDIM) { s.H[i >> 5][i & 31] = 0.0f; s.C[i >> 5][i & 31] = 0.0f; }
  __syncthreads();

  bool uni = true;
  {
    const float d0 = s.Dom[0];
    for (int i = 0; i < 144; ++i) uni = uni && (s.Dom[i] == d0);
  }
  const float dom0 = s.Dom[0];

  // ================= ENCODER =================
  for (int t = 0; t < 8; ++t) {
    if (tid < 64) s.Mask[tid] = gimask[(b * 64 + tid) * 8 + t];
    if (tid < 128) {
      int p = tid >> 1, f = tid & 1;
      s.Xprev[p][f] = gx[((b * 64 + p) * 8 + t) * 2 + f];
    }
    __syncthreads();
    {  // W-build (8 cols/thread) + rowsum shuffle + E-build
      const int i = tid >> 3, g = tid & 7, j8 = g * 8;
      const float mi = s.Mask[i];
      const int gbase = (((b * 64 + i) * 8 + t) << 6) + j8;
      float w[8];
      if (uni) {
        const float4 dv0 = *(const float4*)&gdmat[gbase];
        const float4 dv1 = *(const float4*)&gdmat[gbase + 4];
        w[0] = fmaxf(dom0 - dv0.x, 0.0f) * mi * s.Mask[j8 + 0];
        w[1] = fmaxf(dom0 - dv0.y, 0.0f) * mi * s.Mask[j8 + 1];
        w[2] = fmaxf(dom0 - dv0.z, 0.0f) * mi * s.Mask[j8 + 2];
        w[3] = fmaxf(dom0 - dv0.w, 0.0f) * mi * s.Mask[j8 + 3];
        w[4] = fmaxf(dom0 - dv1.x, 0.0f) * mi * s.Mask[j8 + 4];
        w[5] = fmaxf(dom0 - dv1.y, 0.0f) * mi * s.Mask[j8 + 5];
        w[6] = fmaxf(dom0 - dv1.z, 0.0f) * mi * s.Mask[j8 + 6];
        w[7] = fmaxf(dom0 - dv1.w, 0.0f) * mi * s.Mask[j8 + 7];
      } else {
        #pragma unroll
        for (int c = 0; c < 8; ++c) {
          int gi = gbase + c;
          float dv = gdmat[gi], bv = gbmat[gi], hv = ghmat[gi];
          int ibn = (int)floorf(bv * (1.0f / 30.0f)); ibn = ibn < 0 ? 0 : (ibn > 11 ? 11 : ibn);
          int ihn = (int)floorf(hv * (1.0f / 30.0f)); ihn = ihn < 0 ? 0 : (ihn > 11 ? 11 : ihn);
          w[c] = fmaxf(s.Dom[ihn * 12 + ibn] - dv, 0.0f) * mi * s.Mask[j8 + c];
        }
      }
      *(float4*)&s.W[i][j8]     = make_float4(w[0], w[1], w[2], w[3]);
      *(float4*)&s.W[i][j8 + 4] = make_float4(w[4], w[5], w[6], w[7]);
      float tot = ((w[0] + w[1]) + (w[2] + w[3])) + ((w[4] + w[5]) + (w[6] + w[7]));
      tot += __shfl_xor(tot, 1); tot += __shfl_xor(tot, 2); tot += __shfl_xor(tot, 4);
      if (g == 0) s.RS[i] = 1.0f / (tot + 1e-8f);
      {
        const int p = tid >> 3, k2a = (tid & 7) * 2;
        s.u.eb.E[p][k2a]     = s.Xprev[p][0] * s.Wemb[k2a][0]     + s.Xprev[p][1] * s.Wemb[k2a][1]     + s.Bemb[k2a];
        s.u.eb.E[p][k2a + 1] = s.Xprev[p][0] * s.Wemb[k2a + 1][0] + s.Xprev[p][1] * s.Wemb[k2a + 1][1] + s.Bemb[k2a + 1];
      }
    }
    __syncthreads();
    lstm_g(tid, s, s.H, gWihE, gWhhE, s.BsumE);
    __syncthreads();
    {  // spatial attention + tanh -> carry h and Enc[t]
      const int k2 = tid & 31, ig = tid >> 5, i0 = ig * 4;
      float acc[4] = {};
      #pragma unroll
      for (int c = 0; c < 16; ++c) {
        float h0 = s.HC[c * 4 + 0][k2], h1 = s.HC[c * 4 + 1][k2];
        float h2 = s.HC[c * 4 + 2][k2], h3 = s.HC[c * 4 + 3][k2];
        #pragma unroll
        for (int ii = 0; ii < 4; ++ii) {
          float4 wv = *(const float4*)&s.W[i0 + ii][c * 4];
          acc[ii] += wv.x * h0 + wv.y * h1 + wv.z * h2 + wv.w * h3;
        }
      }
      #pragma unroll
      for (int ii = 0; ii < 4; ++ii) {
        int i = i0 + ii;
        float v = ftanh(acc[ii] * s.RS[i]);
        s.H[i][k2] = v;
        if constexpr (GV) encg[((t << 6) + i) * 32 + k2] = v;
        else              s.Enc[t][i * 33 + k2] = v;
      }
    }
    __syncthreads();
  }

  // ================= DECODER =================
  for (int i = tid; i < 2048; i += BDIM) s.C[i >> 5][i & 31] = 0.0f;
  if (tid < 128) {
    int p = tid >> 1, f = tid & 1;
    s.Xprev[p][f] = gx[((b * 64 + p) * 8 + 7) * 2 + f];
  }
  if (tid < 64) s.Mask[tid] = gimask[(b * 64 + tid) * 8 + 7];
  __syncthreads();
  // W/RS for decoder step 0 == encoder t=7 (still resident)

  for (int sd = 0; sd < 12; ++sd) {
    {  // phase A: E-build + spatial attn on carry h -> Emb
      {
        const int p = tid >> 3, k2a = (tid & 7) * 2;
        s.u.eb.E[p][k2a]     = s.Xprev[p][0] * s.Wemb[k2a][0]     + s.Xprev[p][1] * s.Wemb[k2a][1]     + s.Bemb[k2a];
        s.u.eb.E[p][k2a + 1] = s.Xprev[p][0] * s.Wemb[k2a + 1][0] + s.Xprev[p][1] * s.Wemb[k2a + 1][1] + s.Bemb[k2a + 1];
      }
      const int k2 = tid & 31, ig = tid >> 5, i0 = ig * 4;
      float acc[4] = {};
      #pragma unroll
      for (int c = 0; c < 16; ++c) {
        float h0 = s.H[c * 4 + 0][k2], h1 = s.H[c * 4 + 1][k2];
        float h2 = s.H[c * 4 + 2][k2], h3 = s.H[c * 4 + 3][k2];
        #pragma unroll
        for (int ii = 0; ii < 4; ++ii) {
          float4 wv = *(const float4*)&s.W[i0 + ii][c * 4];
          acc[ii] += wv.x * h0 + wv.y * h1 + wv.z * h2 + wv.w * h3;
        }
      }
      #pragma unroll
      for (int ii = 0; ii < 4; ++ii)
        s.u.eb.Emb[i0 + ii][k2] = ftanh(acc[ii] * s.RS[i0 + ii]);
    }
    __syncthreads();
    lstm_g(tid, s, s.u.eb.Emb, gWihD, gWhhD, s.BsumD);
    __syncthreads();
    {  // temporal attention: thread = (p = tid>>3, t8 = tid&7)
      const int p = tid >> 3, t8 = tid & 7;
      if constexpr (GV) {
        const float4* erow = (const float4*)(encg + (((t8 << 6) + p) << 5));
        float4 er[8];
        #pragma unroll
        for (int c = 0; c < 8; ++c) er[c] = erow[c];
        const float4* hcr = (const float4*)s.HC[p];   // stride 36 -> 16B aligned, bcast
        float sc = 0.0f;
        #pragma unroll
        for (int c = 0; c < 8; ++c) {
          float4 h4 = hcr[c];
          sc += er[c].x * h4.x + er[c].y * h4.y + er[c].z * h4.z + er[c].w * h4.w;
        }
        sc *= 0.17677669529663687f;
        float m = gimask[(b * 64 + p) * 8 + t8];
        sc = (m > 0.0f) ? sc : -1e9f;
        float mx = sc;
        mx = fmaxf(mx, __shfl_xor(mx, 1));
        mx = fmaxf(mx, __shfl_xor(mx, 2));
        mx = fmaxf(mx, __shfl_xor(mx, 4));
        float e = __expf(sc - mx);
        float den = e;
        den += __shfl_xor(den, 1);
        den += __shfl_xor(den, 2);
        den += __shfl_xor(den, 4);
        float a = e / den;
        #pragma unroll
        for (int c = 0; c < 8; ++c) { er[c].x *= a; er[c].y *= a; er[c].z *= a; er[c].w *= a; }
        #pragma unroll
        for (int st = 1; st < 8; st <<= 1) {
          #pragma unroll
          for (int c = 0; c < 8; ++c) {
            er[c].x += __shfl_xor(er[c].x, st);
            er[c].y += __shfl_xor(er[c].y, st);
            er[c].z += __shfl_xor(er[c].z, st);
            er[c].w += __shfl_xor(er[c].w, st);
          }
        }
        // every lane holds full ctx[p][0..31]; lane t8 writes its 4-word slice
        float* cr = &s.u.Ctx[p][t8 * 4];
        float4 v = er[t8];
        cr[0] = v.x; cr[1] = v.y; cr[2] = v.z; cr[3] = v.w;
      } else {
        const float* hcr = s.HC[p];
        const float* enr = &s.Enc[t8][p * 33];
        float sc = 0.0f;
        #pragma unroll
        for (int k2 = 0; k2 < 32; ++k2) sc += hcr[k2] * enr[k2];
        sc *= 0.17677669529663687f;
        float m = gimask[(b * 64 + p) * 8 + t8];
        sc = (m > 0.0f) ? sc : -1e9f;
        float mx = sc;
        mx = fmaxf(mx, __shfl_xor(mx, 1));
        mx = fmaxf(mx, __shfl_xor(mx, 2));
        mx = fmaxf(mx, __shfl_xor(mx, 4));
        float e = __expf(sc - mx);
        float den = e;
        den += __shfl_xor(den, 1);
        den += __shfl_xor(den, 2);
        den += __shfl_xor(den, 4);
        float a = e / den;
        float av[8];
        #pragma unroll
        for (int tt = 0; tt < 8; ++tt) av[tt] = __shfl(a, tt, 8);
        const int kb = t8 * 4;
        float c0 = 0, c1 = 0, c2 = 0, c3 = 0;
        #pragma unroll
        for (int tt = 0; tt < 8; ++tt) {
          const float* er2 = &s.Enc[tt][p * 33 + kb];
          c0 += av[tt] * er2[0]; c1 += av[tt] * er2[1];
          c2 += av[tt] * er2[2]; c3 += av[tt] * er2[3];
        }
        s.u.Ctx[p][kb] = c0; s.u.Ctx[p][kb + 1] = c1;
        s.u.Ctx[p][kb + 2] = c2; s.u.Ctx[p][kb + 3] = c3;
      }
    }
    __syncthreads();
    {  // wtemp (+ fused x_out via 32-lane shuffle reduce)
      const int kp = tid & 31, pg = tid >> 5;
      float r0[4], r1[4];
      #pragma unroll
      for (int pi = 0; pi < 4; ++pi) {
        const int p = pg * 4 + pi;
        float a = s.Btemp[kp];
        #pragma unroll
        for (int m = 0; m < 32; ++m) a += s.u.Ctx[p][m] * __bfloat162float(s.WtT[m][kp]);
        #pragma unroll
        for (int m = 0; m < 32; ++m) a += s.HC[p][m] * __bfloat162float(s.WtT[32 + m][kp]);
        float hv = ftanh(a);
        s.H[p][kp] = hv;
        r0[pi] = hv * s.Wout[0][kp];
        r1[pi] = hv * s.Wout[1][kp];
      }
      #pragma unroll
      for (int st = 1; st < 32; st <<= 1) {
        #pragma unroll
        for (int pi = 0; pi < 4; ++pi) {
          r0[pi] += __shfl_xor(r0[pi], st);
          r1[pi] += __shfl_xor(r1[pi], st);
        }
      }
      if (kp == 0) {
        const int p0 = pg * 4;
        float* go = &gout[((b * 64 + p0) * 12 + sd) * 2];
        #pragma unroll
        for (int pi = 0; pi < 4; ++pi) {
          float vx = ftanh(r0[pi] + s.Bout[0]);
          float vy = ftanh(r1[pi] + s.Bout[1]);
          s.Xout[p0 + pi][0] = vx; s.Xout[p0 + pi][1] = vy;
          go[pi * 24] = vx; go[pi * 24 + 1] = vy;
        }
      }
    }
    __syncthreads();
    if (sd < 11) {
      if (uni) {
        const int i = tid >> 3, g = tid & 7, j8 = g * 8;
        const float v0 = s.MV[2], v1 = s.MV[3];
        const float xi0 = s.Xout[i][0], xi1 = s.Xout[i][1];
        const float mi = s.Mask[i];
        float w[8];
        #pragma unroll
        for (int c = 0; c < 8; ++c) {
          const int j = j8 + c;
          float rx = (s.Xout[j][0] - xi0) * v0;
          float ry = (s.Xout[j][1] - xi1) * v1;
          float dist = sqrtf(rx * rx + ry * ry + 1e-12f);
          w[c] = fmaxf(dom0 - dist, 0.0f) * mi * s.Mask[j];
        }
        *(float4*)&s.W[i][j8]     = make_float4(w[0], w[1], w[2], w[3]);
        *(float4*)&s.W[i][j8 + 4] = make_float4(w[4], w[5], w[6], w[7]);
        float tot = ((w[0] + w[1]) + (w[2] + w[3])) + ((w[4] + w[5]) + (w[6] + w[7]));
        tot += __shfl_xor(tot, 1); tot += __shfl_xor(tot, 2); tot += __shfl_xor(tot, 4);
        if (g == 0) s.RS[i] = 1.0f / (tot + 1e-8f);
        if (tid < 128) { int p = tid >> 1, f = tid & 1; s.Xprev[p][f] = s.Xout[p][f]; }
      } else {
        if (tid < 64) {
          const int p = tid;
          float m0 = s.MV[0], m1 = s.MV[1], v0 = s.MV[2], v1 = s.MV[3];
          float px = s.Xout[p][0] * v0 + m0, py = s.Xout[p][1] * v1 + m1;
          float qx = s.Xprev[p][0] * v0 + m0, qy = s.Xprev[p][1] * v1 + m1;
          s.Head[p] = mod360(atan2_deg(py - qy, px - qx));
          s.Pos[p][0] = px; s.Pos[p][1] = py;
        }
        __syncthreads();
        const int i = tid >> 3, g = tid & 7, j8 = g * 8;
        const float mi = s.Mask[i], hi = s.Head[i];
        const float pix = s.Pos[i][0], piy = s.Pos[i][1];
        float w[8];
        #pragma unroll
        for (int c = 0; c < 8; ++c) {
          const int j = j8 + c;
          float rx = s.Pos[j][0] - pix;
          float ry = s.Pos[j][1] - piy;
          float dist = sqrtf(rx * rx + ry * ry + 1e-12f);
          float rb = mod360(atan2_deg(ry, rx) - hi);
          float rh = mod360(s.Head[j] - hi);
          int ibn = (int)floorf(rb * (1.0f / 30.0f)); ibn = ibn < 0 ? 0 : (ibn > 11 ? 11 : ibn);
          int ihn = (int)floorf(rh * (1.0f / 30.0f)); ihn = ihn < 0 ? 0 : (ihn > 11 ? 11 : ihn);
          w[c] = fmaxf(s.Dom[ihn * 12 + ibn] - dist, 0.0f) * mi * s.Mask[j];
        }
        *(float4*)&s.W[i][j8]     = make_float4(w[0], w[1], w[2], w[3]);
        *(float4*)&s.W[i][j8 + 4] = make_float4(w[4], w[5], w[6], w[7]);
        float tot = ((w[0] + w[1]) + (w[2] + w[3])) + ((w[4] + w[5]) + (w[6] + w[7]));
        tot += __shfl_xor(tot, 1); tot += __shfl_xor(tot, 2); tot += __shfl_xor(tot, 4);
        if (g == 0) s.RS[i] = 1.0f / (tot + 1e-8f);
        if (tid < 128) { int p = tid >> 1, f = tid & 1; s.Xprev[p][f] = s.Xout[p][f]; }
      }
      __syncthreads();
    }
  }
}

extern "C" void kernel_launch(void* const* d_in, const int* in_sizes, int n_in,
                              void* d_out, int out_size, void* d_ws, size_t ws_size,
                              hipStream_t stream) {
  (void)in_sizes; (void)n_in; (void)out_size;
  const float* a0  = (const float*)d_in[0];
  const float* a1  = (const float*)d_in[1];
  const float* a2  = (const float*)d_in[2];
  const float* a3  = (const float*)d_in[3];
  const float* a4  = (const float*)d_in[4];
  const float* a7  = (const float*)d_in[7];
  const float* a8  = (const float*)d_in[8];
  const float* a9  = (const float*)d_in[9];
  const float* a10 = (const float*)d_in[10];
  const float* a11 = (const float*)d_in[11];
  const float* a12 = (const float*)d_in[12];
  const float* a13 = (const float*)d_in[13];
  const float* a14 = (const float*)d_in[14];
  const float* a15 = (const float*)d_in[15];
  const float* a16 = (const float*)d_in[16];
  const float* a17 = (const float*)d_in[17];
  const float* a18 = (const float*)d_in[18];
  const float* a19 = (const float*)d_in[19];
  const float* a20 = (const float*)d_in[20];
  const float* a21 = (const float*)d_in[21];
  const float* a22 = (const float*)d_in[22];
  const float* a23 = (const float*)d_in[23];
  const size_t need = (size_t)512 * 8 * 64 * 32 * sizeof(float);  // 33.5 MB
  if (ws_size >= need) {
    traj_fwd<true><<<512, BDIM, 0, stream>>>(a0, a1, a2, a3, a4, a7, a8, a9, a10,
        a11, a12, a13, a14, a15, a16, a17, a18, a19, a20, a21, a22, a23,
        (float*)d_out, (float*)d_ws);
  } else {
    traj_fwd<false><<<512, BDIM, 0, stream>>>(a0, a1, a2, a3, a4, a7, a8, a9, a10,
        a11, a12, a13, a14, a15, a16, a17, a18, a19, a20, a21, a22, a23,
        (float*)d_out, nullptr);
  }
}

// Round 9
// 412.820 us; speedup vs baseline: 2.7542x; 2.7542x over previous
//
#include <hip/hip_runtime.h>
#include <hip/hip_bf16.h>
#include <math.h>

#define BDIM 512
typedef __hip_bfloat16 bf16;

// Device buffers confirmed float32.
// Ledger of dead ends (r4-r8):
//  - BDIM=1024 -> allocator pins 64 VGPR (launch_bounds & waves_per_eu ignored) -> spills.
//  - 2 blocks/CU at 64KB LDS: does not co-reside (occupancy stayed 23.5%) -> LDS diet pointless.
//  - LSTM weights from global: 32-line gather per instr, L1-thrashed -> 1GB L2-miss traffic.
//  - Enc in global scratch: +400MB latency-bound reads on decoder critical path.
// Proven config: BDIM=512, __launch_bounds__(512,2), weights+Enc in LDS, 128 VGPR.

__device__ __forceinline__ float sigm(float v)  { return 1.0f / (1.0f + __expf(-v)); }
__device__ __forceinline__ float ftanh(float v) { return 1.0f - 2.0f / (__expf(2.0f * v) + 1.0f); }
__device__ __forceinline__ float mod360(float v){ return v - 360.0f * floorf(v * (1.0f / 360.0f)); }

__device__ __forceinline__ float atan2_deg(float y, float x) {
  float ax = fabsf(x), ay = fabsf(y);
  float mx = fmaxf(ax, ay), mn = fminf(ax, ay);
  float r = mn / fmaxf(mx, 1e-30f);
  float r2 = r * r;
  float a = r * (0.99997726f + r2 * (-0.33262347f + r2 * (0.19354346f +
            r2 * (-0.11643287f + r2 * (0.05265332f - r2 * 0.01172120f)))));
  if (ay > ax) a = 1.5707963267948966f - a;
  if (x < 0.0f) a = 3.141592653589793f - a;
  a = copysignf(a, y);
  return a * 57.29577951308232f;
}

union EU {
  float E[64][16];                 // embedding (live: step start -> LSTM)
  float Ctx[64][36];               // temporal ctx (live: temporal -> wtemp), f4-aligned rows
  struct { float Pos[64][2]; float Head[64]; } sp;  // slow path only (live: Wnext phase)
};

struct Smem {
  alignas(16) float H[64][32];     // carry h
  alignas(16) float C[64][32];     // carry c
  alignas(16) float HC[64][36];    // lstm out (stride 36: f4-aligned)
  alignas(16) float Emb[64][32];   // decoder spatial out
  alignas(16) EU u;
  float Enc[8][2120];              // [t][p*33+k]; stride 33 = conflict-optimal for temporal
  alignas(16) float W[64][68];     // spatial weights
  float RS[64];
  alignas(8) bf16 WtTT[32][68];    // W_temp row-major bf16, padded row (2-way banks on uint2)
  alignas(16) float WL[128][52];   // LSTM weights [j][ih(16)|hh(32)|pad]
  float Wemb[16][2];
  float Bemb[16];
  float BsumE[128], BsumD[128];
  float Dom[144];
  float Btemp[32];
  float Wout[2][32];
  float Bout[2];
  float Mask[64];
  unsigned int MaskBits[64];       // bit t = (input_mask[p][t] > 0)
  float Xprev[64][2];
  float Xout[64][2];
  float MV[4];
};
static_assert(sizeof(Smem) <= 160 * 1024, "LDS over budget");

__device__ __forceinline__ void stage_wl(int tid, Smem& s,
    const float* __restrict__ Wih, const float* __restrict__ Whh) {
  for (int idx = tid; idx < 128 * 48; idx += BDIM) {
    int j = idx / 48, m = idx - j * 48;
    s.WL[j][m] = (m < 16) ? Wih[j * 16 + m] : Whh[j * 32 + (m - 16)];
  }
}

// LSTM: thread (k=tid&31, pg=tid>>5) -> 4 gates x 4 pedestrians; weights from LDS.
__device__ __forceinline__ void lstm_stream(int tid, Smem& s,
    const float (*Hin)[32], const float* __restrict__ bsum) {
  const int k = tid & 31, pg = tid >> 5, p0 = pg * 4;
  const float4* W0 = (const float4*)s.WL[k];
  const float4* W1 = (const float4*)s.WL[32 + k];
  const float4* W2 = (const float4*)s.WL[64 + k];
  const float4* W3 = (const float4*)s.WL[96 + k];
  float a0[4], a1[4], a2[4], a3[4];
  {
    const float b0 = bsum[k], b1 = bsum[32 + k], b2 = bsum[64 + k], b3 = bsum[96 + k];
    #pragma unroll
    for (int pi = 0; pi < 4; ++pi) { a0[pi] = b0; a1[pi] = b1; a2[pi] = b2; a3[pi] = b3; }
  }
  #pragma unroll
  for (int m4 = 0; m4 < 4; ++m4) {           // embedding part
    float4 w0 = W0[m4], w1 = W1[m4], w2 = W2[m4], w3 = W3[m4];
    #pragma unroll
    for (int pi = 0; pi < 4; ++pi) {
      float4 xv = ((const float4*)s.u.E[p0 + pi])[m4];
      a0[pi] += xv.x * w0.x + xv.y * w0.y + xv.z * w0.z + xv.w * w0.w;
      a1[pi] += xv.x * w1.x + xv.y * w1.y + xv.z * w1.z + xv.w * w1.w;
      a2[pi] += xv.x * w2.x + xv.y * w2.y + xv.z * w2.z + xv.w * w2.w;
      a3[pi] += xv.x * w3.x + xv.y * w3.y + xv.z * w3.z + xv.w * w3.w;
    }
  }
  #pragma unroll
  for (int m4 = 0; m4 < 8; ++m4) {           // hidden part
    float4 w0 = W0[4 + m4], w1 = W1[4 + m4], w2 = W2[4 + m4], w3 = W3[4 + m4];
    #pragma unroll
    for (int pi = 0; pi < 4; ++pi) {
      float4 hv = ((const float4*)Hin[p0 + pi])[m4];
      a0[pi] += hv.x * w0.x + hv.y * w0.y + hv.z * w0.z + hv.w * w0.w;
      a1[pi] += hv.x * w1.x + hv.y * w1.y + hv.z * w1.z + hv.w * w1.w;
      a2[pi] += hv.x * w2.x + hv.y * w2.y + hv.z * w2.z + hv.w * w2.w;
      a3[pi] += hv.x * w3.x + hv.y * w3.y + hv.z * w3.z + hv.w * w3.w;
    }
  }
  #pragma unroll
  for (int pi = 0; pi < 4; ++pi) {
    const int p = p0 + pi;
    float iv = sigm(a0[pi]), fv = sigm(a1[pi]);
    float gv = ftanh(a2[pi]), ov = sigm(a3[pi]);
    float cn = fv * s.C[p][k] + iv * gv;
    s.C[p][k] = cn;
    s.HC[p][k] = ov * ftanh(cn);
  }
}

__global__ __launch_bounds__(BDIM, 2) void traj_fwd(
    const float* __restrict__ gx, const float* __restrict__ gdmat,
    const float* __restrict__ gbmat, const float* __restrict__ ghmat,
    const float* __restrict__ gimask,
    const float* __restrict__ gmean, const float* __restrict__ gvar,
    const float* __restrict__ gWemb, const float* __restrict__ gbemb,
    const float* __restrict__ gWihE, const float* __restrict__ gWhhE,
    const float* __restrict__ gbihE, const float* __restrict__ gbhhE,
    const float* __restrict__ gWihD, const float* __restrict__ gWhhD,
    const float* __restrict__ gbihD, const float* __restrict__ gbhhD,
    const float* __restrict__ gdom, const float* __restrict__ gWtemp,
    const float* __restrict__ gbtemp, const float* __restrict__ gWout,
    const float* __restrict__ gbout, float* __restrict__ gout)
{
  __shared__ Smem s;
  const int b = blockIdx.x, tid = threadIdx.x;

  // ---- stage constants; zero state; stage encoder LSTM weights ----
  for (int i = tid; i < 128; i += BDIM) {
    s.BsumE[i] = gbihE[i] + gbhhE[i];
    s.BsumD[i] = gbihD[i] + gbhhD[i];
  }
  for (int i = tid; i < 2048; i += BDIM) {
    int kp = i >> 6, m = i & 63;               // gWtemp [32][64] row-major
    s.WtTT[kp][m] = __float2bfloat16(gWtemp[i]);
  }
  for (int i = tid; i < 144; i += BDIM) s.Dom[i] = gdom[i];
  if (tid < 32) s.Btemp[tid] = gbtemp[tid];
  if (tid < 64) s.Wout[tid >> 5][tid & 31] = gWout[tid];
  if (tid < 2)  s.Bout[tid] = gbout[tid];
  if (tid < 16) s.Bemb[tid] = gbemb[tid];
  if (tid < 32) s.Wemb[tid >> 1][tid & 1] = gWemb[tid];
  if (tid < 4)  s.MV[tid] = (tid < 2) ? gmean[b * 2 + tid] : gvar[b * 2 + tid - 2];
  for (int i = tid; i < 2048; i += BDIM) { s.H[i >> 5][i & 31] = 0.0f; s.C[i >> 5][i & 31] = 0.0f; }
  stage_wl(tid, s, gWihE, gWhhE);
  __syncthreads();

  // Uniform-domain fast path detect (exact shortcut: domain[ih,ib] == Dom[0]).
  bool uni = true;
  {
    const float d0 = s.Dom[0];
    for (int i = 0; i < 144; ++i) uni = uni && (s.Dom[i] == d0);
  }
  const float dom0 = s.Dom[0];

  // ================= ENCODER =================
  for (int t = 0; t < 8; ++t) {
    if (tid < 64) s.Mask[tid] = gimask[(b * 64 + tid) * 8 + t];
    if (tid < 128) {
      int p = tid >> 1, f = tid & 1;
      s.Xprev[p][f] = gx[((b * 64 + p) * 8 + t) * 2 + f];
    }
    __syncthreads();
    {  // W-build (8 cols/thread) + rowsum via shuffle + E-build
      const int i = tid >> 3, g = tid & 7, j8 = g * 8;
      const float mi = s.Mask[i];
      const int gbase = (((b * 64 + i) * 8 + t) << 6) + j8;
      float w[8];
      if (uni) {
        const float4 dv0 = *(const float4*)&gdmat[gbase];
        const float4 dv1 = *(const float4*)&gdmat[gbase + 4];
        w[0] = fmaxf(dom0 - dv0.x, 0.0f) * mi * s.Mask[j8 + 0];
        w[1] = fmaxf(dom0 - dv0.y, 0.0f) * mi * s.Mask[j8 + 1];
        w[2] = fmaxf(dom0 - dv0.z, 0.0f) * mi * s.Mask[j8 + 2];
        w[3] = fmaxf(dom0 - dv0.w, 0.0f) * mi * s.Mask[j8 + 3];
        w[4] = fmaxf(dom0 - dv1.x, 0.0f) * mi * s.Mask[j8 + 4];
        w[5] = fmaxf(dom0 - dv1.y, 0.0f) * mi * s.Mask[j8 + 5];
        w[6] = fmaxf(dom0 - dv1.z, 0.0f) * mi * s.Mask[j8 + 6];
        w[7] = fmaxf(dom0 - dv1.w, 0.0f) * mi * s.Mask[j8 + 7];
      } else {
        #pragma unroll
        for (int c = 0; c < 8; ++c) {
          int gi = gbase + c;
          float dv = gdmat[gi], bv = gbmat[gi], hv = ghmat[gi];
          int ibn = (int)floorf(bv * (1.0f / 30.0f)); ibn = ibn < 0 ? 0 : (ibn > 11 ? 11 : ibn);
          int ihn = (int)floorf(hv * (1.0f / 30.0f)); ihn = ihn < 0 ? 0 : (ihn > 11 ? 11 : ihn);
          w[c] = fmaxf(s.Dom[ihn * 12 + ibn] - dv, 0.0f) * mi * s.Mask[j8 + c];
        }
      }
      *(float4*)&s.W[i][j8]     = make_float4(w[0], w[1], w[2], w[3]);
      *(float4*)&s.W[i][j8 + 4] = make_float4(w[4], w[5], w[6], w[7]);
      float tot = ((w[0] + w[1]) + (w[2] + w[3])) + ((w[4] + w[5]) + (w[6] + w[7]));
      tot += __shfl_xor(tot, 1); tot += __shfl_xor(tot, 2); tot += __shfl_xor(tot, 4);
      if (g == 0) s.RS[i] = 1.0f / (tot + 1e-8f);
      {
        const int p = tid >> 3, k2a = (tid & 7) * 2;
        s.u.E[p][k2a]     = s.Xprev[p][0] * s.Wemb[k2a][0]     + s.Xprev[p][1] * s.Wemb[k2a][1]     + s.Bemb[k2a];
        s.u.E[p][k2a + 1] = s.Xprev[p][0] * s.Wemb[k2a + 1][0] + s.Xprev[p][1] * s.Wemb[k2a + 1][1] + s.Bemb[k2a + 1];
      }
    }
    __syncthreads();
    lstm_stream(tid, s, s.H, s.BsumE);
    __syncthreads();
    {  // spatial attention + tanh -> carry h and Enc[t]
      const int k2 = tid & 31, ig = tid >> 5, i0 = ig * 4;
      float acc[4] = {};
      #pragma unroll
      for (int c = 0; c < 16; ++c) {
        float h0 = s.HC[c * 4 + 0][k2], h1 = s.HC[c * 4 + 1][k2];
        float h2 = s.HC[c * 4 + 2][k2], h3 = s.HC[c * 4 + 3][k2];
        #pragma unroll
        for (int ii = 0; ii < 4; ++ii) {
          float4 wv = *(const float4*)&s.W[i0 + ii][c * 4];
          acc[ii] += wv.x * h0 + wv.y * h1 + wv.z * h2 + wv.w * h3;
        }
      }
      #pragma unroll
      for (int ii = 0; ii < 4; ++ii) {
        int i = i0 + ii;
        float v = ftanh(acc[ii] * s.RS[i]);
        s.H[i][k2] = v;
        s.Enc[t][i * 33 + k2] = v;
      }
    }
    __syncthreads();
  }

  // ================= DECODER =================
  stage_wl(tid, s, gWihD, gWhhD);
  for (int i = tid; i < 2048; i += BDIM) s.C[i >> 5][i & 31] = 0.0f;
  if (tid < 128) {
    int p = tid >> 1, f = tid & 1;
    s.Xprev[p][f] = gx[((b * 64 + p) * 8 + 7) * 2 + f];
  }
  if (tid < 64) {
    s.Mask[tid] = gimask[(b * 64 + tid) * 8 + 7];
    const float4 m0 = *(const float4*)&gimask[(b * 64 + tid) * 8];
    const float4 m1 = *(const float4*)&gimask[(b * 64 + tid) * 8 + 4];
    unsigned int mb = 0;
    mb |= (m0.x > 0.0f) ? 1u : 0u;  mb |= (m0.y > 0.0f) ? 2u : 0u;
    mb |= (m0.z > 0.0f) ? 4u : 0u;  mb |= (m0.w > 0.0f) ? 8u : 0u;
    mb |= (m1.x > 0.0f) ? 16u : 0u; mb |= (m1.y > 0.0f) ? 32u : 0u;
    mb |= (m1.z > 0.0f) ? 64u : 0u; mb |= (m1.w > 0.0f) ? 128u : 0u;
    s.MaskBits[tid] = mb;
  }
  __syncthreads();
  // W/RS for decoder step 0 == encoder t=7 (still resident)

  for (int sd = 0; sd < 12; ++sd) {
    {  // phase A: E-build + spatial attn on carry h -> Emb
      {
        const int p = tid >> 3, k2a = (tid & 7) * 2;
        s.u.E[p][k2a]     = s.Xprev[p][0] * s.Wemb[k2a][0]     + s.Xprev[p][1] * s.Wemb[k2a][1]     + s.Bemb[k2a];
        s.u.E[p][k2a + 1] = s.Xprev[p][0] * s.Wemb[k2a + 1][0] + s.Xprev[p][1] * s.Wemb[k2a + 1][1] + s.Bemb[k2a + 1];
      }
      const int k2 = tid & 31, ig = tid >> 5, i0 = ig * 4;
      float acc[4] = {};
      #pragma unroll
      for (int c = 0; c < 16; ++c) {
        float h0 = s.H[c * 4 + 0][k2], h1 = s.H[c * 4 + 1][k2];
        float h2 = s.H[c * 4 + 2][k2], h3 = s.H[c * 4 + 3][k2];
        #pragma unroll
        for (int ii = 0; ii < 4; ++ii) {
          float4 wv = *(const float4*)&s.W[i0 + ii][c * 4];
          acc[ii] += wv.x * h0 + wv.y * h1 + wv.z * h2 + wv.w * h3;
        }
      }
      #pragma unroll
      for (int ii = 0; ii < 4; ++ii)
        s.Emb[i0 + ii][k2] = ftanh(acc[ii] * s.RS[i0 + ii]);
    }
    __syncthreads();
    lstm_stream(tid, s, s.Emb, s.BsumD);
    __syncthreads();
    {  // temporal attention: thread = (p = tid>>3, t8 = tid&7)
      const int p = tid >> 3, t8 = tid & 7;
      const float* hcr = s.HC[p];
      const float* enr = &s.Enc[t8][p * 33];
      float sc = 0.0f;
      #pragma unroll
      for (int k2 = 0; k2 < 32; ++k2) sc += hcr[k2] * enr[k2];
      sc *= 0.17677669529663687f;   // 1/sqrt(32)
      sc = ((s.MaskBits[p] >> t8) & 1u) ? sc : -1e9f;
      float mx = sc;
      mx = fmaxf(mx, __shfl_xor(mx, 1));
      mx = fmaxf(mx, __shfl_xor(mx, 2));
      mx = fmaxf(mx, __shfl_xor(mx, 4));
      float e = __expf(sc - mx);
      float den = e;
      den += __shfl_xor(den, 1);
      den += __shfl_xor(den, 2);
      den += __shfl_xor(den, 4);
      float a = e / den;
      float av[8];
      #pragma unroll
      for (int tt = 0; tt < 8; ++tt) av[tt] = __shfl(a, tt, 8);
      const int kb = t8 * 4;
      float c0 = 0, c1 = 0, c2 = 0, c3 = 0;
      #pragma unroll
      for (int tt = 0; tt < 8; ++tt) {
        const float* er = &s.Enc[tt][p * 33 + kb];
        c0 += av[tt] * er[0]; c1 += av[tt] * er[1];
        c2 += av[tt] * er[2]; c3 += av[tt] * er[3];
      }
      s.u.Ctx[p][kb] = c0; s.u.Ctx[p][kb + 1] = c1;
      s.u.Ctx[p][kb + 2] = c2; s.u.Ctx[p][kb + 3] = c3;
    }
    __syncthreads();
    {  // wtemp: f4 act reads + hoisted bf16 weight row (uint2, shift-convert)
      const int kp = tid & 31, pg = tid >> 5;
      const uint2* wrow = (const uint2*)s.WtTT[kp];
      float acc[4];
      #pragma unroll
      for (int pi = 0; pi < 4; ++pi) acc[pi] = s.Btemp[kp];
      #pragma unroll
      for (int mc = 0; mc < 16; ++mc) {
        const uint2 w2 = wrow[mc];
        const float f0 = __uint_as_float(w2.x << 16);
        const float f1 = __uint_as_float(w2.x & 0xFFFF0000u);
        const float f2 = __uint_as_float(w2.y << 16);
        const float f3 = __uint_as_float(w2.y & 0xFFFF0000u);
        #pragma unroll
        for (int pi = 0; pi < 4; ++pi) {
          const int p = pg * 4 + pi;
          const float4 av = (mc < 8) ? *(const float4*)&s.u.Ctx[p][mc * 4]
                                     : *(const float4*)&s.HC[p][(mc - 8) * 4];
          acc[pi] += av.x * f0 + av.y * f1 + av.z * f2 + av.w * f3;
        }
      }
      float r0[4], r1[4];
      #pragma unroll
      for (int pi = 0; pi < 4; ++pi) {
        float hv = ftanh(acc[pi]);
        s.H[pg * 4 + pi][kp] = hv;
        r0[pi] = hv * s.Wout[0][kp];
        r1[pi] = hv * s.Wout[1][kp];
      }
      #pragma unroll
      for (int st = 1; st < 32; st <<= 1) {
        #pragma unroll
        for (int pi = 0; pi < 4; ++pi) {
          r0[pi] += __shfl_xor(r0[pi], st);
          r1[pi] += __shfl_xor(r1[pi], st);
        }
      }
      if (kp == 0) {
        const int p0 = pg * 4;
        float* go = &gout[((b * 64 + p0) * 12 + sd) * 2];
        #pragma unroll
        for (int pi = 0; pi < 4; ++pi) {
          float vx = ftanh(r0[pi] + s.Bout[0]);
          float vy = ftanh(r1[pi] + s.Bout[1]);
          s.Xout[p0 + pi][0] = vx; s.Xout[p0 + pi][1] = vy;
          go[pi * 24] = vx; go[pi * 24 + 1] = vy;
        }
      }
    }
    __syncthreads();
    if (sd < 11) {
      if (uni) {
        const int i = tid >> 3, g = tid & 7, j8 = g * 8;
        const float v0 = s.MV[2], v1 = s.MV[3];
        const float xi0 = s.Xout[i][0], xi1 = s.Xout[i][1];
        const float mi = s.Mask[i];
        float w[8];
        #pragma unroll
        for (int c = 0; c < 8; ++c) {
          const int j = j8 + c;
          float rx = (s.Xout[j][0] - xi0) * v0;
          float ry = (s.Xout[j][1] - xi1) * v1;
          float dist = sqrtf(rx * rx + ry * ry + 1e-12f);
          w[c] = fmaxf(dom0 - dist, 0.0f) * mi * s.Mask[j];
        }
        *(float4*)&s.W[i][j8]     = make_float4(w[0], w[1], w[2], w[3]);
        *(float4*)&s.W[i][j8 + 4] = make_float4(w[4], w[5], w[6], w[7]);
        float tot = ((w[0] + w[1]) + (w[2] + w[3])) + ((w[4] + w[5]) + (w[6] + w[7]));
        tot += __shfl_xor(tot, 1); tot += __shfl_xor(tot, 2); tot += __shfl_xor(tot, 4);
        if (g == 0) s.RS[i] = 1.0f / (tot + 1e-8f);
        if (tid < 128) { int p = tid >> 1, f = tid & 1; s.Xprev[p][f] = s.Xout[p][f]; }
      } else {
        if (tid < 64) {
          const int p = tid;
          float m0 = s.MV[0], m1 = s.MV[1], v0 = s.MV[2], v1 = s.MV[3];
          float px = s.Xout[p][0] * v0 + m0, py = s.Xout[p][1] * v1 + m1;
          float qx = s.Xprev[p][0] * v0 + m0, qy = s.Xprev[p][1] * v1 + m1;
          s.u.sp.Head[p] = mod360(atan2_deg(py - qy, px - qx));
          s.u.sp.Pos[p][0] = px; s.u.sp.Pos[p][1] = py;
        }
        __syncthreads();
        const int i = tid >> 3, g = tid & 7, j8 = g * 8;
        const float mi = s.Mask[i], hi = s.u.sp.Head[i];
        const float pix = s.u.sp.Pos[i][0], piy = s.u.sp.Pos[i][1];
        float w[8];
        #pragma unroll
        for (int c = 0; c < 8; ++c) {
          const int j = j8 + c;
          float rx = s.u.sp.Pos[j][0] - pix;
          float ry = s.u.sp.Pos[j][1] - piy;
          float dist = sqrtf(rx * rx + ry * ry + 1e-12f);
          float rb = mod360(atan2_deg(ry, rx) - hi);
          float rh = mod360(s.u.sp.Head[j] - hi);
          int ibn = (int)floorf(rb * (1.0f / 30.0f)); ibn = ibn < 0 ? 0 : (ibn > 11 ? 11 : ibn);
          int ihn = (int)floorf(rh * (1.0f / 30.0f)); ihn = ihn < 0 ? 0 : (ihn > 11 ? 11 : ihn);
          w[c] = fmaxf(s.Dom[ihn * 12 + ibn] - dist, 0.0f) * mi * s.Mask[j];
        }
        *(float4*)&s.W[i][j8]     = make_float4(w[0], w[1], w[2], w[3]);
        *(float4*)&s.W[i][j8 + 4] = make_float4(w[4], w[5], w[6], w[7]);
        float tot = ((w[0] + w[1]) + (w[2] + w[3])) + ((w[4] + w[5]) + (w[6] + w[7]));
        tot += __shfl_xor(tot, 1); tot += __shfl_xor(tot, 2); tot += __shfl_xor(tot, 4);
        if (g == 0) s.RS[i] = 1.0f / (tot + 1e-8f);
        if (tid < 128) { int p = tid >> 1, f = tid & 1; s.Xprev[p][f] = s.Xout[p][f]; }
      }
      __syncthreads();
    }
  }
}

extern "C" void kernel_launch(void* const* d_in, const int* in_sizes, int n_in,
                              void* d_out, int out_size, void* d_ws, size_t ws_size,
                              hipStream_t stream) {
  (void)in_sizes; (void)n_in; (void)d_ws; (void)ws_size; (void)out_size;
  traj_fwd<<<512, BDIM, 0, stream>>>(
      (const float*)d_in[0], (const float*)d_in[1], (const float*)d_in[2],
      (const float*)d_in[3], (const float*)d_in[4],
      /* d_in[5] output_mask, d_in[6] scene unused */
      (const float*)d_in[7], (const float*)d_in[8],
      (const float*)d_in[9], (const float*)d_in[10],
      (const float*)d_in[11], (const float*)d_in[12],
      (const float*)d_in[13], (const float*)d_in[14],
      (const float*)d_in[15], (const float*)d_in[16],
      (const float*)d_in[17], (const float*)d_in[18],
      (const float*)d_in[19], (const float*)d_in[20],
      (const float*)d_in[21], (const float*)d_in[22], (const float*)d_in[23],
      (float*)d_out);
}

// Round 10
// 382.351 us; speedup vs baseline: 2.9737x; 1.0797x over previous
//
#include <hip/hip_runtime.h>
#include <hip/hip_bf16.h>
#include <math.h>

#define BDIM 512
typedef __hip_bfloat16 bf16;

// Device buffers confirmed float32.
// Dead-end ledger (r4-r8): BDIM=1024 -> 64-VGPR pin + spills; 2 blocks/CU never
// co-resides (occupancy stuck 23.5%); LSTM weights from global -> L1-thrash 1GB;
// Enc in global scratch -> latency-bound decoder. Proven: BDIM=512, (512,2),
// weights+Enc in LDS. r7 vs r3: VALU cuts alone don't move the wall ->
// LDS-issue + barrier bound. This round: E-fold (-33% LSTM) + wave-ownership
// schedule (84 -> ~30 barriers, H/Xout double-buffered).

__device__ __forceinline__ float sigm(float v)  { return 1.0f / (1.0f + __expf(-v)); }
__device__ __forceinline__ float ftanh(float v) { return 1.0f - 2.0f / (__expf(2.0f * v) + 1.0f); }
__device__ __forceinline__ float mod360(float v){ return v - 360.0f * floorf(v * (1.0f / 360.0f)); }

__device__ __forceinline__ float atan2_deg(float y, float x) {
  float ax = fabsf(x), ay = fabsf(y);
  float mx = fmaxf(ax, ay), mn = fminf(ax, ay);
  float r = mn / fmaxf(mx, 1e-30f);
  float r2 = r * r;
  float a = r * (0.99997726f + r2 * (-0.33262347f + r2 * (0.19354346f +
            r2 * (-0.11643287f + r2 * (0.05265332f - r2 * 0.01172120f)))));
  if (ay > ax) a = 1.5707963267948966f - a;
  if (x < 0.0f) a = 3.141592653589793f - a;
  a = copysignf(a, y);
  return a * 57.29577951308232f;
}

struct Smem {
  alignas(16) float H[2][64][32];  // double-buffered carry h (A reads [sd&1], wtemp writes [sd&1^1])
  alignas(16) float C[64][32];     // carry c (own-rows only)
  alignas(16) float HC[64][36];    // lstm out (stride 36: f4-aligned, conflict-spread)
  union EU {
    float EmbCtx[64][32];          // Emb (A->LSTM) then Ctx (temporal->wtemp); same-row/same-wave overlay
    struct { float Pos[64][2]; float Head[64]; } sp;  // slow path only
  };
  alignas(16) EU u;
  float Enc[8][2112];              // [t][p*33+k]
  alignas(16) float W[64][68];     // spatial weights
  float RS[64];
  alignas(8) bf16 WtTT[32][68];    // W_temp row-major bf16, padded rows
  alignas(16) float WL[128][36];   // LSTM hidden weights only (K=32; E folded out)
  float VxE0[128], VxE1[128];      // folded x-coefficients: Wih . Wemb[:,f]
  float VxD0[128], VxD1[128];
  float BsumE[128], BsumD[128];    // bih + bhh + Wih.bemb (E-fold bias)
  float Dom[144];
  float Btemp[32];
  float Wout[2][32];
  float Bout[2];
  float MaskF[8][64];              // all masks, staged once
  unsigned int MaskBits[64];
  float Xprev[64][2];
  float Xout[2][64][2];            // double-buffered
  float MV[4];
};
static_assert(sizeof(Smem) <= 160 * 1024, "LDS over budget");

// LSTM: thread (k=tid&31, pg=tid>>5) -> 4 gates x 4 own pedestrians.
// Pre-activation = Bsum + x0*Vx0 + x1*Vx1 + Whh.h  (embedding folded).
__device__ __forceinline__ void lstm2(int tid, Smem& s,
    const float (*Hin)[32], const float* __restrict__ bsum,
    const float* __restrict__ vx0, const float* __restrict__ vx1) {
  const int k = tid & 31, pg = tid >> 5, p0 = pg * 4;
  const float4* W0 = (const float4*)s.WL[k];
  const float4* W1 = (const float4*)s.WL[32 + k];
  const float4* W2 = (const float4*)s.WL[64 + k];
  const float4* W3 = (const float4*)s.WL[96 + k];
  const float v00 = vx0[k],      v01 = vx1[k];
  const float v10 = vx0[32 + k], v11 = vx1[32 + k];
  const float v20 = vx0[64 + k], v21 = vx1[64 + k];
  const float v30 = vx0[96 + k], v31 = vx1[96 + k];
  const float b0 = bsum[k], b1 = bsum[32 + k], b2 = bsum[64 + k], b3 = bsum[96 + k];
  float a0[4], a1[4], a2[4], a3[4];
  #pragma unroll
  for (int pi = 0; pi < 4; ++pi) {
    const int p = p0 + pi;
    const float x0 = s.Xprev[p][0], x1 = s.Xprev[p][1];
    a0[pi] = b0 + x0 * v00 + x1 * v01;
    a1[pi] = b1 + x0 * v10 + x1 * v11;
    a2[pi] = b2 + x0 * v20 + x1 * v21;
    a3[pi] = b3 + x0 * v30 + x1 * v31;
  }
  #pragma unroll
  for (int m4 = 0; m4 < 8; ++m4) {
    float4 w0 = W0[m4], w1 = W1[m4], w2 = W2[m4], w3 = W3[m4];
    #pragma unroll
    for (int pi = 0; pi < 4; ++pi) {
      float4 hv = ((const float4*)Hin[p0 + pi])[m4];
      a0[pi] += hv.x * w0.x + hv.y * w0.y + hv.z * w0.z + hv.w * w0.w;
      a1[pi] += hv.x * w1.x + hv.y * w1.y + hv.z * w1.z + hv.w * w1.w;
      a2[pi] += hv.x * w2.x + hv.y * w2.y + hv.z * w2.z + hv.w * w2.w;
      a3[pi] += hv.x * w3.x + hv.y * w3.y + hv.z * w3.z + hv.w * w3.w;
    }
  }
  #pragma unroll
  for (int pi = 0; pi < 4; ++pi) {
    const int p = p0 + pi;
    float iv = sigm(a0[pi]), fv = sigm(a1[pi]);
    float gv = ftanh(a2[pi]), ov = sigm(a3[pi]);
    float cn = fv * s.C[p][k] + iv * gv;
    s.C[p][k] = cn;
    s.HC[p][k] = ov * ftanh(cn);
  }
}

__global__ __launch_bounds__(BDIM, 2) void traj_fwd(
    const float* __restrict__ gx, const float* __restrict__ gdmat,
    const float* __restrict__ gbmat, const float* __restrict__ ghmat,
    const float* __restrict__ gimask,
    const float* __restrict__ gmean, const float* __restrict__ gvar,
    const float* __restrict__ gWemb, const float* __restrict__ gbemb,
    const float* __restrict__ gWihE, const float* __restrict__ gWhhE,
    const float* __restrict__ gbihE, const float* __restrict__ gbhhE,
    const float* __restrict__ gWihD, const float* __restrict__ gWhhD,
    const float* __restrict__ gbihD, const float* __restrict__ gbhhD,
    const float* __restrict__ gdom, const float* __restrict__ gWtemp,
    const float* __restrict__ gbtemp, const float* __restrict__ gWout,
    const float* __restrict__ gbout, float* __restrict__ gout)
{
  __shared__ Smem s;
  const int b = blockIdx.x, tid = threadIdx.x;

  // ================= PROLOGUE (one barrier) =================
  if (tid < 128) {   // E-fold: Vx = Wih.Wemb[:,f], bias += Wih.bemb
    float be = 0, bd = 0, e0 = 0, e1 = 0, d0 = 0, d1 = 0;
    #pragma unroll
    for (int k = 0; k < 16; ++k) {
      const float wE = gWihE[tid * 16 + k], wD = gWihD[tid * 16 + k];
      const float w0 = gWemb[k * 2 + 0], w1 = gWemb[k * 2 + 1], bb = gbemb[k];
      e0 += wE * w0; e1 += wE * w1; be += wE * bb;
      d0 += wD * w0; d1 += wD * w1; bd += wD * bb;
    }
    s.VxE0[tid] = e0; s.VxE1[tid] = e1;
    s.VxD0[tid] = d0; s.VxD1[tid] = d1;
    s.BsumE[tid] = gbihE[tid] + gbhhE[tid] + be;
    s.BsumD[tid] = gbihD[tid] + gbhhD[tid] + bd;
  }
  for (int i = tid; i < 2048; i += BDIM) {
    int kp = i >> 6, m = i & 63;
    s.WtTT[kp][m] = __float2bfloat16(gWtemp[i]);
  }
  for (int i = tid; i < 144; i += BDIM) s.Dom[i] = gdom[i];
  if (tid < 32) s.Btemp[tid] = gbtemp[tid];
  if (tid < 64) s.Wout[tid >> 5][tid & 31] = gWout[tid];
  if (tid < 2)  s.Bout[tid] = gbout[tid];
  if (tid < 4)  s.MV[tid] = (tid < 2) ? gmean[b * 2 + tid] : gvar[b * 2 + tid - 2];
  for (int i = tid; i < 512; i += BDIM) {    // MaskF[t][p]
    int t = i >> 6, p = i & 63;
    s.MaskF[t][p] = gimask[(b * 64 + p) * 8 + t];
  }
  if (tid < 64) {
    const float4 m0 = *(const float4*)&gimask[(b * 64 + tid) * 8];
    const float4 m1 = *(const float4*)&gimask[(b * 64 + tid) * 8 + 4];
    unsigned int mb = 0;
    mb |= (m0.x > 0.0f) ? 1u : 0u;  mb |= (m0.y > 0.0f) ? 2u : 0u;
    mb |= (m0.z > 0.0f) ? 4u : 0u;  mb |= (m0.w > 0.0f) ? 8u : 0u;
    mb |= (m1.x > 0.0f) ? 16u : 0u; mb |= (m1.y > 0.0f) ? 32u : 0u;
    mb |= (m1.z > 0.0f) ? 64u : 0u; mb |= (m1.w > 0.0f) ? 128u : 0u;
    s.MaskBits[tid] = mb;
  }
  for (int idx = tid; idx < 128 * 32; idx += BDIM) {  // encoder Whh
    int j = idx >> 5, m = idx & 31;
    s.WL[j][m] = gWhhE[j * 32 + m];
  }
  for (int i = tid; i < 2048; i += BDIM) { s.H[0][i >> 5][i & 31] = 0.0f; s.C[i >> 5][i & 31] = 0.0f; }
  __syncthreads();

  bool uni = true;
  {
    const float d0 = s.Dom[0];
    for (int i = 0; i < 144; ++i) uni = uni && (s.Dom[i] == d0);
  }
  const float dom0 = s.Dom[0];

  // ================= ENCODER (2 barriers/iter) =================
  for (int t = 0; t < 8; ++t) {
    const int he = t & 1;
    {  // P1: W-build (8 cols/thread) + rowsum shuffle + Xprev own-load
      const int i = tid >> 3, g = tid & 7, j8 = g * 8;
      const float mi = s.MaskF[t][i];
      const int gbase = (((b * 64 + i) * 8 + t) << 6) + j8;
      float w[8];
      if (uni) {
        const float4 dv0 = *(const float4*)&gdmat[gbase];
        const float4 dv1 = *(const float4*)&gdmat[gbase + 4];
        w[0] = fmaxf(dom0 - dv0.x, 0.0f) * mi * s.MaskF[t][j8 + 0];
        w[1] = fmaxf(dom0 - dv0.y, 0.0f) * mi * s.MaskF[t][j8 + 1];
        w[2] = fmaxf(dom0 - dv0.z, 0.0f) * mi * s.MaskF[t][j8 + 2];
        w[3] = fmaxf(dom0 - dv0.w, 0.0f) * mi * s.MaskF[t][j8 + 3];
        w[4] = fmaxf(dom0 - dv1.x, 0.0f) * mi * s.MaskF[t][j8 + 4];
        w[5] = fmaxf(dom0 - dv1.y, 0.0f) * mi * s.MaskF[t][j8 + 5];
        w[6] = fmaxf(dom0 - dv1.z, 0.0f) * mi * s.MaskF[t][j8 + 6];
        w[7] = fmaxf(dom0 - dv1.w, 0.0f) * mi * s.MaskF[t][j8 + 7];
      } else {
        #pragma unroll
        for (int c = 0; c < 8; ++c) {
          int gi = gbase + c;
          float dv = gdmat[gi], bv = gbmat[gi], hv = ghmat[gi];
          int ibn = (int)floorf(bv * (1.0f / 30.0f)); ibn = ibn < 0 ? 0 : (ibn > 11 ? 11 : ibn);
          int ihn = (int)floorf(hv * (1.0f / 30.0f)); ihn = ihn < 0 ? 0 : (ihn > 11 ? 11 : ihn);
          w[c] = fmaxf(s.Dom[ihn * 12 + ibn] - dv, 0.0f) * mi * s.MaskF[t][j8 + c];
        }
      }
      *(float4*)&s.W[i][j8]     = make_float4(w[0], w[1], w[2], w[3]);
      *(float4*)&s.W[i][j8 + 4] = make_float4(w[4], w[5], w[6], w[7]);
      float tot = ((w[0] + w[1]) + (w[2] + w[3])) + ((w[4] + w[5]) + (w[6] + w[7]));
      tot += __shfl_xor(tot, 1); tot += __shfl_xor(tot, 2); tot += __shfl_xor(tot, 4);
      if (g == 0) {
        s.RS[i] = 1.0f / (tot + 1e-8f);
        s.Xprev[i][0] = gx[((b * 64 + i) * 8 + t) * 2];
        s.Xprev[i][1] = gx[((b * 64 + i) * 8 + t) * 2 + 1];
      }
    }
    // P2: LSTM (own rows; Xprev own; no barrier needed after P1)
    lstm2(tid, s, s.H[he], s.BsumE, s.VxE0, s.VxE1);
    __syncthreads();   // barA: HC(all-waves) -> P3 reads all rows
    {  // P3: spatial attention + tanh -> H[he^1] own rows + Enc[t]
      const int k2 = tid & 31, ig = tid >> 5, i0 = ig * 4;
      float acc[4] = {};
      #pragma unroll
      for (int c = 0; c < 16; ++c) {
        float h0 = s.HC[c * 4 + 0][k2], h1 = s.HC[c * 4 + 1][k2];
        float h2 = s.HC[c * 4 + 2][k2], h3 = s.HC[c * 4 + 3][k2];
        #pragma unroll
        for (int ii = 0; ii < 4; ++ii) {
          float4 wv = *(const float4*)&s.W[i0 + ii][c * 4];
          acc[ii] += wv.x * h0 + wv.y * h1 + wv.z * h2 + wv.w * h3;
        }
      }
      #pragma unroll
      for (int ii = 0; ii < 4; ++ii) {
        int i = i0 + ii;
        float v = ftanh(acc[ii] * s.RS[i]);
        s.H[he ^ 1][i][k2] = v;
        s.Enc[t][i * 33 + k2] = v;
      }
    }
    __syncthreads();   // barB: P3's HC-all-reads done before next P2 writes HC
  }

  // ================= DECODER START =================
  for (int idx = tid; idx < 128 * 32; idx += BDIM) {   // decoder Whh
    int j = idx >> 5, m = idx & 31;
    s.WL[j][m] = gWhhD[j * 32 + m];
  }
  for (int i = tid; i < 2048; i += BDIM) s.C[i >> 5][i & 31] = 0.0f;
  if (tid < 128) {
    int p = tid >> 1, f = tid & 1;
    s.Xprev[p][f] = gx[((b * 64 + p) * 8 + 7) * 2 + f];
  }
  __syncthreads();
  // W/RS persist from encoder t=7; h_enc is in H[0].

  // ================= DECODER (1 barrier/step on fast path) =================
  for (int sd = 0; sd < 12; ++sd) {
    const int cur = sd & 1;
    {  // A: spatial attn on H[cur] (reads all rows; RAW via prev bar1) -> Emb own
      const int k2 = tid & 31, ig = tid >> 5, i0 = ig * 4;
      float acc[4] = {};
      #pragma unroll
      for (int c = 0; c < 16; ++c) {
        float h0 = s.H[cur][c * 4 + 0][k2], h1 = s.H[cur][c * 4 + 1][k2];
        float h2 = s.H[cur][c * 4 + 2][k2], h3 = s.H[cur][c * 4 + 3][k2];
        #pragma unroll
        for (int ii = 0; ii < 4; ++ii) {
          float4 wv = *(const float4*)&s.W[i0 + ii][c * 4];
          acc[ii] += wv.x * h0 + wv.y * h1 + wv.z * h2 + wv.w * h3;
        }
      }
      #pragma unroll
      for (int ii = 0; ii < 4; ++ii)
        s.u.EmbCtx[i0 + ii][k2] = ftanh(acc[ii] * s.RS[i0 + ii]);
    }
    // LSTM: reads Emb own + Xprev own (same wave)
    lstm2(tid, s, s.u.EmbCtx, s.BsumD, s.VxD0, s.VxD1);
    {  // temporal: thread = (p = tid>>3 own, t8 = tid&7); HC own rows
      const int p = tid >> 3, t8 = tid & 7;
      const float* hcr = s.HC[p];
      const float* enr = &s.Enc[t8][p * 33];
      float sc = 0.0f;
      #pragma unroll
      for (int k2 = 0; k2 < 32; ++k2) sc += hcr[k2] * enr[k2];
      sc *= 0.17677669529663687f;
      sc = ((s.MaskBits[p] >> t8) & 1u) ? sc : -1e9f;
      float mx = sc;
      mx = fmaxf(mx, __shfl_xor(mx, 1));
      mx = fmaxf(mx, __shfl_xor(mx, 2));
      mx = fmaxf(mx, __shfl_xor(mx, 4));
      float e = __expf(sc - mx);
      float den = e;
      den += __shfl_xor(den, 1);
      den += __shfl_xor(den, 2);
      den += __shfl_xor(den, 4);
      float a = e / den;
      float av[8];
      #pragma unroll
      for (int tt = 0; tt < 8; ++tt) av[tt] = __shfl(a, tt, 8);
      const int kb = t8 * 4;
      float c0 = 0, c1 = 0, c2 = 0, c3 = 0;
      #pragma unroll
      for (int tt = 0; tt < 8; ++tt) {
        const float* er = &s.Enc[tt][p * 33 + kb];
        c0 += av[tt] * er[0]; c1 += av[tt] * er[1];
        c2 += av[tt] * er[2]; c3 += av[tt] * er[3];
      }
      // overwrite own Emb rows with Ctx (same-row, same-wave union)
      *(float4*)&s.u.EmbCtx[p][kb] = make_float4(c0, c1, c2, c3);
    }
    {  // wtemp + fused x_out: Ctx own, HC own -> H[cur^1] own + Xout[cur] own
      const int kp = tid & 31, pg = tid >> 5;
      const uint2* wrow = (const uint2*)s.WtTT[kp];
      float acc[4];
      #pragma unroll
      for (int pi = 0; pi < 4; ++pi) acc[pi] = s.Btemp[kp];
      #pragma unroll
      for (int mc = 0; mc < 16; ++mc) {
        const uint2 w2 = wrow[mc];
        const float f0 = __uint_as_float(w2.x << 16);
        const float f1 = __uint_as_float(w2.x & 0xFFFF0000u);
        const float f2 = __uint_as_float(w2.y << 16);
        const float f3 = __uint_as_float(w2.y & 0xFFFF0000u);
        #pragma unroll
        for (int pi = 0; pi < 4; ++pi) {
          const int p = pg * 4 + pi;
          const float4 av = (mc < 8) ? *(const float4*)&s.u.EmbCtx[p][mc * 4]
                                     : *(const float4*)&s.HC[p][(mc - 8) * 4];
          acc[pi] += av.x * f0 + av.y * f1 + av.z * f2 + av.w * f3;
        }
      }
      float r0[4], r1[4];
      #pragma unroll
      for (int pi = 0; pi < 4; ++pi) {
        float hv = ftanh(acc[pi]);
        s.H[cur ^ 1][pg * 4 + pi][kp] = hv;
        r0[pi] = hv * s.Wout[0][kp];
        r1[pi] = hv * s.Wout[1][kp];
      }
      #pragma unroll
      for (int st = 1; st < 32; st <<= 1) {
        #pragma unroll
        for (int pi = 0; pi < 4; ++pi) {
          r0[pi] += __shfl_xor(r0[pi], st);
          r1[pi] += __shfl_xor(r1[pi], st);
        }
      }
      if (kp == 0) {
        const int p0 = pg * 4;
        float* go = &gout[((b * 64 + p0) * 12 + sd) * 2];
        #pragma unroll
        for (int pi = 0; pi < 4; ++pi) {
          float vx = ftanh(r0[pi] + s.Bout[0]);
          float vy = ftanh(r1[pi] + s.Bout[1]);
          s.Xout[cur][p0 + pi][0] = vx; s.Xout[cur][p0 + pi][1] = vy;
          go[pi * 24] = vx; go[pi * 24 + 1] = vy;
        }
      }
    }
    __syncthreads();   // bar1: Xout[cur] + H[cur^1] visible to all
    if (sd < 11) {
      if (uni) {
        // Wnext fast path: own rows only -> no further barrier this step
        const int i = tid >> 3, g = tid & 7, j8 = g * 8;
        const float v0 = s.MV[2], v1 = s.MV[3];
        const float xi0 = s.Xout[cur][i][0], xi1 = s.Xout[cur][i][1];
        const float mi = s.MaskF[7][i];
        float w[8];
        #pragma unroll
        for (int c = 0; c < 8; ++c) {
          const int j = j8 + c;
          float rx = (s.Xout[cur][j][0] - xi0) * v0;
          float ry = (s.Xout[cur][j][1] - xi1) * v1;
          float dist = sqrtf(rx * rx + ry * ry + 1e-12f);
          w[c] = fmaxf(dom0 - dist, 0.0f) * mi * s.MaskF[7][j];
        }
        *(float4*)&s.W[i][j8]     = make_float4(w[0], w[1], w[2], w[3]);
        *(float4*)&s.W[i][j8 + 4] = make_float4(w[4], w[5], w[6], w[7]);
        float tot = ((w[0] + w[1]) + (w[2] + w[3])) + ((w[4] + w[5]) + (w[6] + w[7]));
        tot += __shfl_xor(tot, 1); tot += __shfl_xor(tot, 2); tot += __shfl_xor(tot, 4);
        if (g == 0) {
          s.RS[i] = 1.0f / (tot + 1e-8f);
          s.Xprev[i][0] = s.Xout[cur][i][0];
          s.Xprev[i][1] = s.Xout[cur][i][1];
        }
      } else {
        // slow path: Pos/Head overlay u.sp (Ctx reads finished pre-bar1)
        if (tid < 64) {
          const int p = tid;
          float m0 = s.MV[0], m1 = s.MV[1], v0 = s.MV[2], v1 = s.MV[3];
          float px = s.Xout[cur][p][0] * v0 + m0, py = s.Xout[cur][p][1] * v1 + m1;
          float qx = s.Xprev[p][0] * v0 + m0, qy = s.Xprev[p][1] * v1 + m1;
          s.u.sp.Head[p] = mod360(atan2_deg(py - qy, px - qx));
          s.u.sp.Pos[p][0] = px; s.u.sp.Pos[p][1] = py;
        }
        __syncthreads();
        const int i = tid >> 3, g = tid & 7, j8 = g * 8;
        const float mi = s.MaskF[7][i], hi = s.u.sp.Head[i];
        const float pix = s.u.sp.Pos[i][0], piy = s.u.sp.Pos[i][1];
        float w[8];
        #pragma unroll
        for (int c = 0; c < 8; ++c) {
          const int j = j8 + c;
          float rx = s.u.sp.Pos[j][0] - pix;
          float ry = s.u.sp.Pos[j][1] - piy;
          float dist = sqrtf(rx * rx + ry * ry + 1e-12f);
          float rb = mod360(atan2_deg(ry, rx) - hi);
          float rh = mod360(s.u.sp.Head[j] - hi);
          int ibn = (int)floorf(rb * (1.0f / 30.0f)); ibn = ibn < 0 ? 0 : (ibn > 11 ? 11 : ibn);
          int ihn = (int)floorf(rh * (1.0f / 30.0f)); ihn = ihn < 0 ? 0 : (ihn > 11 ? 11 : ihn);
          w[c] = fmaxf(s.Dom[ihn * 12 + ibn] - dist, 0.0f) * mi * s.MaskF[7][j];
        }
        *(float4*)&s.W[i][j8]     = make_float4(w[0], w[1], w[2], w[3]);
        *(float4*)&s.W[i][j8 + 4] = make_float4(w[4], w[5], w[6], w[7]);
        float tot = ((w[0] + w[1]) + (w[2] + w[3])) + ((w[4] + w[5]) + (w[6] + w[7]));
        tot += __shfl_xor(tot, 1); tot += __shfl_xor(tot, 2); tot += __shfl_xor(tot, 4);
        if (g == 0) {
          s.RS[i] = 1.0f / (tot + 1e-8f);
          s.Xprev[i][0] = s.Xout[cur][i][0];
          s.Xprev[i][1] = s.Xout[cur][i][1];
        }
        __syncthreads();  // sp reads done before next A overwrites EmbCtx
      }
    }
  }
}

extern "C" void kernel_launch(void* const* d_in, const int* in_sizes, int n_in,
                              void* d_out, int out_size, void* d_ws, size_t ws_size,
                              hipStream_t stream) {
  (void)in_sizes; (void)n_in; (void)d_ws; (void)ws_size; (void)out_size;
  traj_fwd<<<512, BDIM, 0, stream>>>(
      (const float*)d_in[0], (const float*)d_in[1], (const float*)d_in[2],
      (const float*)d_in[3], (const float*)d_in[4],
      /* d_in[5] output_mask, d_in[6] scene unused */
      (const float*)d_in[7], (const float*)d_in[8],
      (const float*)d_in[9], (const float*)d_in[10],
      (const float*)d_in[11], (const float*)d_in[12],
      (const float*)d_in[13], (const float*)d_in[14],
      (const float*)d_in[15], (const float*)d_in[16],
      (const float*)d_in[17], (const float*)d_in[18],
      (const float*)d_in[19], (const float*)d_in[20],
      (const float*)d_in[21], (const float*)d_in[22], (const float*)d_in[23],
      (float*)d_out);
}

// Round 11
// 359.727 us; speedup vs baseline: 3.1607x; 1.0629x over previous
//
#include <hip/hip_runtime.h>
#include <hip/hip_bf16.h>
#include <math.h>

#define BDIM 512
typedef __hip_bfloat16 bf16;

// Device buffers confirmed float32.
// Dead-end ledger (r4-r8): BDIM=1024 -> 64-VGPR pin + spills; 2 blocks/CU never
// co-resides; LSTM weights from global -> L1-thrash; Enc in global -> latency.
// r10 lesson: Enc plane stride MUST be != 0 mod 32 (2112 gave 8-way conflicts on
// temporal reads, +19M conflict cycles). 2120 == 8 mod 32 -> 2-way (free).

__device__ __forceinline__ float sigm(float v)  { return 1.0f / (1.0f + __expf(-v)); }
__device__ __forceinline__ float ftanh(float v) { return 1.0f - 2.0f / (__expf(2.0f * v) + 1.0f); }
__device__ __forceinline__ float mod360(float v){ return v - 360.0f * floorf(v * (1.0f / 360.0f)); }

__device__ __forceinline__ float atan2_deg(float y, float x) {
  float ax = fabsf(x), ay = fabsf(y);
  float mx = fmaxf(ax, ay), mn = fminf(ax, ay);
  float r = mn / fmaxf(mx, 1e-30f);
  float r2 = r * r;
  float a = r * (0.99997726f + r2 * (-0.33262347f + r2 * (0.19354346f +
            r2 * (-0.11643287f + r2 * (0.05265332f - r2 * 0.01172120f)))));
  if (ay > ax) a = 1.5707963267948966f - a;
  if (x < 0.0f) a = 3.141592653589793f - a;
  a = copysignf(a, y);
  return a * 57.29577951308232f;
}

struct Smem {
  alignas(16) float H[2][64][32];  // double-buffered carry h
  alignas(16) float C[64][32];     // carry c (own-rows only)
  alignas(16) float HC[64][36];    // lstm out (stride 36: f4-aligned, min-conflict)
  union EU {
    float EmbCtx[64][32];          // Emb (A->LSTM) then Ctx (temporal->wtemp)
    struct { float Pos[64][2]; float Head[64]; } sp;  // slow path only
  };
  alignas(16) EU u;
  float Enc[8][2120];              // [t][p*33+k]; 2120 == 8 mod 32 (bank spread!)
  alignas(16) float W[64][68];     // spatial weights
  float RS[64];
  alignas(8) bf16 WtTT[32][68];    // W_temp row-major bf16, padded rows
  alignas(16) float WL[128][36];   // LSTM hidden weights (K=32; E folded out)
  float VxE0[128], VxE1[128];      // folded x-coefficients: Wih . Wemb[:,f]
  float VxD0[128], VxD1[128];
  float BsumE[128], BsumD[128];    // bih + bhh + Wih.bemb
  float Dom[144];
  float Btemp[32];
  float Wout[2][32];
  float Bout[2];
  float MaskF[8][64];
  unsigned int MaskBits[64];
  float Xprev[64][2];
  float Xout[2][64][2];
  float MV[4];
};
static_assert(sizeof(Smem) <= 160 * 1024, "LDS over budget");

// LSTM: thread (k=tid&31, pg=tid>>5) -> 4 gates x 4 own pedestrians.
__device__ __forceinline__ void lstm2(int tid, Smem& s,
    const float (*Hin)[32], const float* __restrict__ bsum,
    const float* __restrict__ vx0, const float* __restrict__ vx1) {
  const int k = tid & 31, pg = tid >> 5, p0 = pg * 4;
  const float4* W0 = (const float4*)s.WL[k];
  const float4* W1 = (const float4*)s.WL[32 + k];
  const float4* W2 = (const float4*)s.WL[64 + k];
  const float4* W3 = (const float4*)s.WL[96 + k];
  const float v00 = vx0[k],      v01 = vx1[k];
  const float v10 = vx0[32 + k], v11 = vx1[32 + k];
  const float v20 = vx0[64 + k], v21 = vx1[64 + k];
  const float v30 = vx0[96 + k], v31 = vx1[96 + k];
  const float b0 = bsum[k], b1 = bsum[32 + k], b2 = bsum[64 + k], b3 = bsum[96 + k];
  float a0[4], a1[4], a2[4], a3[4];
  #pragma unroll
  for (int pi = 0; pi < 4; ++pi) {
    const int p = p0 + pi;
    const float x0 = s.Xprev[p][0], x1 = s.Xprev[p][1];
    a0[pi] = b0 + x0 * v00 + x1 * v01;
    a1[pi] = b1 + x0 * v10 + x1 * v11;
    a2[pi] = b2 + x0 * v20 + x1 * v21;
    a3[pi] = b3 + x0 * v30 + x1 * v31;
  }
  #pragma unroll
  for (int m4 = 0; m4 < 8; ++m4) {
    float4 w0 = W0[m4], w1 = W1[m4], w2 = W2[m4], w3 = W3[m4];
    #pragma unroll
    for (int pi = 0; pi < 4; ++pi) {
      float4 hv = ((const float4*)Hin[p0 + pi])[m4];
      a0[pi] += hv.x * w0.x + hv.y * w0.y + hv.z * w0.z + hv.w * w0.w;
      a1[pi] += hv.x * w1.x + hv.y * w1.y + hv.z * w1.z + hv.w * w1.w;
      a2[pi] += hv.x * w2.x + hv.y * w2.y + hv.z * w2.z + hv.w * w2.w;
      a3[pi] += hv.x * w3.x + hv.y * w3.y + hv.z * w3.z + hv.w * w3.w;
    }
  }
  #pragma unroll
  for (int pi = 0; pi < 4; ++pi) {
    const int p = p0 + pi;
    float iv = sigm(a0[pi]), fv = sigm(a1[pi]);
    float gv = ftanh(a2[pi]), ov = sigm(a3[pi]);
    float cn = fv * s.C[p][k] + iv * gv;
    s.C[p][k] = cn;
    s.HC[p][k] = ov * ftanh(cn);
  }
}

__global__ __launch_bounds__(BDIM, 2) void traj_fwd(
    const float* __restrict__ gx, const float* __restrict__ gdmat,
    const float* __restrict__ gbmat, const float* __restrict__ ghmat,
    const float* __restrict__ gimask,
    const float* __restrict__ gmean, const float* __restrict__ gvar,
    const float* __restrict__ gWemb, const float* __restrict__ gbemb,
    const float* __restrict__ gWihE, const float* __restrict__ gWhhE,
    const float* __restrict__ gbihE, const float* __restrict__ gbhhE,
    const float* __restrict__ gWihD, const float* __restrict__ gWhhD,
    const float* __restrict__ gbihD, const float* __restrict__ gbhhD,
    const float* __restrict__ gdom, const float* __restrict__ gWtemp,
    const float* __restrict__ gbtemp, const float* __restrict__ gWout,
    const float* __restrict__ gbout, float* __restrict__ gout)
{
  __shared__ Smem s;
  const int b = blockIdx.x, tid = threadIdx.x;

  // ================= PROLOGUE (one barrier) =================
  if (tid < 128) {   // E-fold: Vx = Wih.Wemb[:,f], bias += Wih.bemb
    float be = 0, bd = 0, e0 = 0, e1 = 0, d0 = 0, d1 = 0;
    #pragma unroll
    for (int k = 0; k < 16; ++k) {
      const float wE = gWihE[tid * 16 + k], wD = gWihD[tid * 16 + k];
      const float w0 = gWemb[k * 2 + 0], w1 = gWemb[k * 2 + 1], bb = gbemb[k];
      e0 += wE * w0; e1 += wE * w1; be += wE * bb;
      d0 += wD * w0; d1 += wD * w1; bd += wD * bb;
    }
    s.VxE0[tid] = e0; s.VxE1[tid] = e1;
    s.VxD0[tid] = d0; s.VxD1[tid] = d1;
    s.BsumE[tid] = gbihE[tid] + gbhhE[tid] + be;
    s.BsumD[tid] = gbihD[tid] + gbhhD[tid] + bd;
  }
  for (int i = tid; i < 2048; i += BDIM) {
    int kp = i >> 6, m = i & 63;
    s.WtTT[kp][m] = __float2bfloat16(gWtemp[i]);
  }
  for (int i = tid; i < 144; i += BDIM) s.Dom[i] = gdom[i];
  if (tid < 32) s.Btemp[tid] = gbtemp[tid];
  if (tid < 64) s.Wout[tid >> 5][tid & 31] = gWout[tid];
  if (tid < 2)  s.Bout[tid] = gbout[tid];
  if (tid < 4)  s.MV[tid] = (tid < 2) ? gmean[b * 2 + tid] : gvar[b * 2 + tid - 2];
  for (int i = tid; i < 512; i += BDIM) {
    int t = i >> 6, p = i & 63;
    s.MaskF[t][p] = gimask[(b * 64 + p) * 8 + t];
  }
  if (tid < 64) {
    const float4 m0 = *(const float4*)&gimask[(b * 64 + tid) * 8];
    const float4 m1 = *(const float4*)&gimask[(b * 64 + tid) * 8 + 4];
    unsigned int mb = 0;
    mb |= (m0.x > 0.0f) ? 1u : 0u;  mb |= (m0.y > 0.0f) ? 2u : 0u;
    mb |= (m0.z > 0.0f) ? 4u : 0u;  mb |= (m0.w > 0.0f) ? 8u : 0u;
    mb |= (m1.x > 0.0f) ? 16u : 0u; mb |= (m1.y > 0.0f) ? 32u : 0u;
    mb |= (m1.z > 0.0f) ? 64u : 0u; mb |= (m1.w > 0.0f) ? 128u : 0u;
    s.MaskBits[tid] = mb;
  }
  for (int idx = tid; idx < 128 * 32; idx += BDIM) {
    int j = idx >> 5, m = idx & 31;
    s.WL[j][m] = gWhhE[j * 32 + m];
  }
  for (int i = tid; i < 2048; i += BDIM) { s.H[0][i >> 5][i & 31] = 0.0f; s.C[i >> 5][i & 31] = 0.0f; }
  __syncthreads();

  bool uni = true;
  {
    const float d0 = s.Dom[0];
    for (int i = 0; i < 144; ++i) uni = uni && (s.Dom[i] == d0);
  }
  const float dom0 = s.Dom[0];

  // ================= ENCODER (2 barriers/iter) =================
  for (int t = 0; t < 8; ++t) {
    const int he = t & 1;
    {  // P1: W-build + rowsum shuffle + Xprev own-load
      const int i = tid >> 3, g = tid & 7, j8 = g * 8;
      const float mi = s.MaskF[t][i];
      const int gbase = (((b * 64 + i) * 8 + t) << 6) + j8;
      float w[8];
      if (uni) {
        const float4 dv0 = *(const float4*)&gdmat[gbase];
        const float4 dv1 = *(const float4*)&gdmat[gbase + 4];
        w[0] = fmaxf(dom0 - dv0.x, 0.0f) * mi * s.MaskF[t][j8 + 0];
        w[1] = fmaxf(dom0 - dv0.y, 0.0f) * mi * s.MaskF[t][j8 + 1];
        w[2] = fmaxf(dom0 - dv0.z, 0.0f) * mi * s.MaskF[t][j8 + 2];
        w[3] = fmaxf(dom0 - dv0.w, 0.0f) * mi * s.MaskF[t][j8 + 3];
        w[4] = fmaxf(dom0 - dv1.x, 0.0f) * mi * s.MaskF[t][j8 + 4];
        w[5] = fmaxf(dom0 - dv1.y, 0.0f) * mi * s.MaskF[t][j8 + 5];
        w[6] = fmaxf(dom0 - dv1.z, 0.0f) * mi * s.MaskF[t][j8 + 6];
        w[7] = fmaxf(dom0 - dv1.w, 0.0f) * mi * s.MaskF[t][j8 + 7];
      } else {
        #pragma unroll
        for (int c = 0; c < 8; ++c) {
          int gi = gbase + c;
          float dv = gdmat[gi], bv = gbmat[gi], hv = ghmat[gi];
          int ibn = (int)floorf(bv * (1.0f / 30.0f)); ibn = ibn < 0 ? 0 : (ibn > 11 ? 11 : ibn);
          int ihn = (int)floorf(hv * (1.0f / 30.0f)); ihn = ihn < 0 ? 0 : (ihn > 11 ? 11 : ihn);
          w[c] = fmaxf(s.Dom[ihn * 12 + ibn] - dv, 0.0f) * mi * s.MaskF[t][j8 + c];
        }
      }
      *(float4*)&s.W[i][j8]     = make_float4(w[0], w[1], w[2], w[3]);
      *(float4*)&s.W[i][j8 + 4] = make_float4(w[4], w[5], w[6], w[7]);
      float tot = ((w[0] + w[1]) + (w[2] + w[3])) + ((w[4] + w[5]) + (w[6] + w[7]));
      tot += __shfl_xor(tot, 1); tot += __shfl_xor(tot, 2); tot += __shfl_xor(tot, 4);
      if (g == 0) {
        s.RS[i] = 1.0f / (tot + 1e-8f);
        s.Xprev[i][0] = gx[((b * 64 + i) * 8 + t) * 2];
        s.Xprev[i][1] = gx[((b * 64 + i) * 8 + t) * 2 + 1];
      }
    }
    lstm2(tid, s, s.H[he], s.BsumE, s.VxE0, s.VxE1);
    __syncthreads();   // barA: HC all-rows visible to P3
    {  // P3: spatial attention + tanh -> H[he^1] own rows + Enc[t]
      const int k2 = tid & 31, ig = tid >> 5, i0 = ig * 4;
      float acc[4] = {};
      #pragma unroll
      for (int c = 0; c < 16; ++c) {
        float h0 = s.HC[c * 4 + 0][k2], h1 = s.HC[c * 4 + 1][k2];
        float h2 = s.HC[c * 4 + 2][k2], h3 = s.HC[c * 4 + 3][k2];
        #pragma unroll
        for (int ii = 0; ii < 4; ++ii) {
          float4 wv = *(const float4*)&s.W[i0 + ii][c * 4];
          acc[ii] += wv.x * h0 + wv.y * h1 + wv.z * h2 + wv.w * h3;
        }
      }
      #pragma unroll
      for (int ii = 0; ii < 4; ++ii) {
        int i = i0 + ii;
        float v = ftanh(acc[ii] * s.RS[i]);
        s.H[he ^ 1][i][k2] = v;
        s.Enc[t][i * 33 + k2] = v;
      }
    }
    __syncthreads();   // barB: HC-all-reads done before next P2 writes HC
  }

  // ================= DECODER START =================
  for (int idx = tid; idx < 128 * 32; idx += BDIM) {
    int j = idx >> 5, m = idx & 31;
    s.WL[j][m] = gWhhD[j * 32 + m];
  }
  for (int i = tid; i < 2048; i += BDIM) s.C[i >> 5][i & 31] = 0.0f;
  if (tid < 128) {
    int p = tid >> 1, f = tid & 1;
    s.Xprev[p][f] = gx[((b * 64 + p) * 8 + 7) * 2 + f];
  }
  __syncthreads();
  // W/RS persist from encoder t=7; h_enc is in H[0].

  // ================= DECODER (1 barrier/step on fast path) =================
  for (int sd = 0; sd < 12; ++sd) {
    const int cur = sd & 1;
    {  // A: spatial attn on H[cur] -> Emb own rows
      const int k2 = tid & 31, ig = tid >> 5, i0 = ig * 4;
      float acc[4] = {};
      #pragma unroll
      for (int c = 0; c < 16; ++c) {
        float h0 = s.H[cur][c * 4 + 0][k2], h1 = s.H[cur][c * 4 + 1][k2];
        float h2 = s.H[cur][c * 4 + 2][k2], h3 = s.H[cur][c * 4 + 3][k2];
        #pragma unroll
        for (int ii = 0; ii < 4; ++ii) {
          float4 wv = *(const float4*)&s.W[i0 + ii][c * 4];
          acc[ii] += wv.x * h0 + wv.y * h1 + wv.z * h2 + wv.w * h3;
        }
      }
      #pragma unroll
      for (int ii = 0; ii < 4; ++ii)
        s.u.EmbCtx[i0 + ii][k2] = ftanh(acc[ii] * s.RS[i0 + ii]);
    }
    lstm2(tid, s, s.u.EmbCtx, s.BsumD, s.VxD0, s.VxD1);
    {  // temporal: thread = (p = tid>>3 own, t8 = tid&7)
      const int p = tid >> 3, t8 = tid & 7;
      const float4* h4p = (const float4*)s.HC[p];   // 144B rows: 16B-aligned
      const float* enr = &s.Enc[t8][p * 33];
      float sc = 0.0f;
      #pragma unroll
      for (int c = 0; c < 8; ++c) {
        const float4 h4 = h4p[c];
        sc += h4.x * enr[c * 4 + 0] + h4.y * enr[c * 4 + 1]
            + h4.z * enr[c * 4 + 2] + h4.w * enr[c * 4 + 3];
      }
      sc *= 0.17677669529663687f;
      sc = ((s.MaskBits[p] >> t8) & 1u) ? sc : -1e9f;
      float mx = sc;
      mx = fmaxf(mx, __shfl_xor(mx, 1));
      mx = fmaxf(mx, __shfl_xor(mx, 2));
      mx = fmaxf(mx, __shfl_xor(mx, 4));
      float e = __expf(sc - mx);
      float den = e;
      den += __shfl_xor(den, 1);
      den += __shfl_xor(den, 2);
      den += __shfl_xor(den, 4);
      float a = e / den;
      float av[8];
      #pragma unroll
      for (int tt = 0; tt < 8; ++tt) av[tt] = __shfl(a, tt, 8);
      const int kb = t8 * 4;
      float c0 = 0, c1 = 0, c2 = 0, c3 = 0;
      #pragma unroll
      for (int tt = 0; tt < 8; ++tt) {
        const float* er = &s.Enc[tt][p * 33 + kb];
        c0 += av[tt] * er[0]; c1 += av[tt] * er[1];
        c2 += av[tt] * er[2]; c3 += av[tt] * er[3];
      }
      *(float4*)&s.u.EmbCtx[p][kb] = make_float4(c0, c1, c2, c3);
    }
    {  // wtemp + fused x_out
      const int kp = tid & 31, pg = tid >> 5;
      const uint2* wrow = (const uint2*)s.WtTT[kp];
      float acc[4];
      #pragma unroll
      for (int pi = 0; pi < 4; ++pi) acc[pi] = s.Btemp[kp];
      #pragma unroll
      for (int mc = 0; mc < 16; ++mc) {
        const uint2 w2 = wrow[mc];
        const float f0 = __uint_as_float(w2.x << 16);
        const float f1 = __uint_as_float(w2.x & 0xFFFF0000u);
        const float f2 = __uint_as_float(w2.y << 16);
        const float f3 = __uint_as_float(w2.y & 0xFFFF0000u);
        #pragma unroll
        for (int pi = 0; pi < 4; ++pi) {
          const int p = pg * 4 + pi;
          const float4 av = (mc < 8) ? *(const float4*)&s.u.EmbCtx[p][mc * 4]
                                     : *(const float4*)&s.HC[p][(mc - 8) * 4];
          acc[pi] += av.x * f0 + av.y * f1 + av.z * f2 + av.w * f3;
        }
      }
      float r0[4], r1[4];
      #pragma unroll
      for (int pi = 0; pi < 4; ++pi) {
        float hv = ftanh(acc[pi]);
        s.H[cur ^ 1][pg * 4 + pi][kp] = hv;
        r0[pi] = hv * s.Wout[0][kp];
        r1[pi] = hv * s.Wout[1][kp];
      }
      #pragma unroll
      for (int st = 1; st < 32; st <<= 1) {
        #pragma unroll
        for (int pi = 0; pi < 4; ++pi) {
          r0[pi] += __shfl_xor(r0[pi], st);
          r1[pi] += __shfl_xor(r1[pi], st);
        }
      }
      if (kp == 0) {
        const int p0 = pg * 4;
        float* go = &gout[((b * 64 + p0) * 12 + sd) * 2];
        #pragma unroll
        for (int pi = 0; pi < 4; ++pi) {
          float vx = ftanh(r0[pi] + s.Bout[0]);
          float vy = ftanh(r1[pi] + s.Bout[1]);
          s.Xout[cur][p0 + pi][0] = vx; s.Xout[cur][p0 + pi][1] = vy;
          go[pi * 24] = vx; go[pi * 24 + 1] = vy;
        }
      }
    }
    __syncthreads();   // bar1: Xout[cur] + H[cur^1] visible to all
    if (sd < 11) {
      if (uni) {
        const int i = tid >> 3, g = tid & 7, j8 = g * 8;
        const float v0 = s.MV[2], v1 = s.MV[3];
        const float xi0 = s.Xout[cur][i][0], xi1 = s.Xout[cur][i][1];
        const float mi = s.MaskF[7][i];
        float w[8];
        #pragma unroll
        for (int c = 0; c < 8; ++c) {
          const int j = j8 + c;
          float rx = (s.Xout[cur][j][0] - xi0) * v0;
          float ry = (s.Xout[cur][j][1] - xi1) * v1;
          float dist = sqrtf(rx * rx + ry * ry + 1e-12f);
          w[c] = fmaxf(dom0 - dist, 0.0f) * mi * s.MaskF[7][j];
        }
        *(float4*)&s.W[i][j8]     = make_float4(w[0], w[1], w[2], w[3]);
        *(float4*)&s.W[i][j8 + 4] = make_float4(w[4], w[5], w[6], w[7]);
        float tot = ((w[0] + w[1]) + (w[2] + w[3])) + ((w[4] + w[5]) + (w[6] + w[7]));
        tot += __shfl_xor(tot, 1); tot += __shfl_xor(tot, 2); tot += __shfl_xor(tot, 4);
        if (g == 0) {
          s.RS[i] = 1.0f / (tot + 1e-8f);
          s.Xprev[i][0] = s.Xout[cur][i][0];
          s.Xprev[i][1] = s.Xout[cur][i][1];
        }
      } else {
        if (tid < 64) {
          const int p = tid;
          float m0 = s.MV[0], m1 = s.MV[1], v0 = s.MV[2], v1 = s.MV[3];
          float px = s.Xout[cur][p][0] * v0 + m0, py = s.Xout[cur][p][1] * v1 + m1;
          float qx = s.Xprev[p][0] * v0 + m0, qy = s.Xprev[p][1] * v1 + m1;
          s.u.sp.Head[p] = mod360(atan2_deg(py - qy, px - qx));
          s.u.sp.Pos[p][0] = px; s.u.sp.Pos[p][1] = py;
        }
        __syncthreads();
        const int i = tid >> 3, g = tid & 7, j8 = g * 8;
        const float mi = s.MaskF[7][i], hi = s.u.sp.Head[i];
        const float pix = s.u.sp.Pos[i][0], piy = s.u.sp.Pos[i][1];
        float w[8];
        #pragma unroll
        for (int c = 0; c < 8; ++c) {
          const int j = j8 + c;
          float rx = s.u.sp.Pos[j][0] - pix;
          float ry = s.u.sp.Pos[j][1] - piy;
          float dist = sqrtf(rx * rx + ry * ry + 1e-12f);
          float rb = mod360(atan2_deg(ry, rx) - hi);
          float rh = mod360(s.u.sp.Head[j] - hi);
          int ibn = (int)floorf(rb * (1.0f / 30.0f)); ibn = ibn < 0 ? 0 : (ibn > 11 ? 11 : ibn);
          int ihn = (int)floorf(rh * (1.0f / 30.0f)); ihn = ihn < 0 ? 0 : (ihn > 11 ? 11 : ihn);
          w[c] = fmaxf(s.Dom[ihn * 12 + ibn] - dist, 0.0f) * mi * s.MaskF[7][j];
        }
        *(float4*)&s.W[i][j8]     = make_float4(w[0], w[1], w[2], w[3]);
        *(float4*)&s.W[i][j8 + 4] = make_float4(w[4], w[5], w[6], w[7]);
        float tot = ((w[0] + w[1]) + (w[2] + w[3])) + ((w[4] + w[5]) + (w[6] + w[7]));
        tot += __shfl_xor(tot, 1); tot += __shfl_xor(tot, 2); tot += __shfl_xor(tot, 4);
        if (g == 0) {
          s.RS[i] = 1.0f / (tot + 1e-8f);
          s.Xprev[i][0] = s.Xout[cur][i][0];
          s.Xprev[i][1] = s.Xout[cur][i][1];
        }
        __syncthreads();
      }
    }
  }
}

extern "C" void kernel_launch(void* const* d_in, const int* in_sizes, int n_in,
                              void* d_out, int out_size, void* d_ws, size_t ws_size,
                              hipStream_t stream) {
  (void)in_sizes; (void)n_in; (void)d_ws; (void)ws_size; (void)out_size;
  traj_fwd<<<512, BDIM, 0, stream>>>(
      (const float*)d_in[0], (const float*)d_in[1], (const float*)d_in[2],
      (const float*)d_in[3], (const float*)d_in[4],
      /* d_in[5] output_mask, d_in[6] scene unused */
      (const float*)d_in[7], (const float*)d_in[8],
      (const float*)d_in[9], (const float*)d_in[10],
      (const float*)d_in[11], (const float*)d_in[12],
      (const float*)d_in[13], (const float*)d_in[14],
      (const float*)d_in[15], (const float*)d_in[16],
      (const float*)d_in[17], (const float*)d_in[18],
      (const float*)d_in[19], (const float*)d_in[20],
      (const float*)d_in[21], (const float*)d_in[22], (const float*)d_in[23],
      (float*)d_out);
}